// Round 25
// baseline (1367.925 us; speedup 1.0000x reference)
//
#include <hip/hip_runtime.h>
#include <math.h>

typedef unsigned short u16;
typedef unsigned int u32;
typedef __attribute__((ext_vector_type(8))) short bf16x8;
typedef __attribute__((ext_vector_type(4))) float f32x4;

#define TOK 2048     // B*S
#define SEQ 1024
#define DM 1024
#define NEXP 8
#define VOCAB 32000
#define NL 2
#define SLOTS 5120   // max 64-aligned padded expert rows: 4096 + 8*63 < 5120
#define APAD 40      // padded u16 row for 32-k tiles (80B)

__device__ __forceinline__ float bf2f(u16 v) {
  u32 u = ((u32)v) << 16; float f; __builtin_memcpy(&f, &u, 4); return f;
}
__device__ __forceinline__ u16 f2bf(float f) {
  u32 u; __builtin_memcpy(&u, &f, 4);
  u += 0x7fffu + ((u >> 16) & 1u);   // RNE
  return (u16)(u >> 16);
}
__device__ __forceinline__ void split8(const float* v, u16* hi, u16* lo) {
#pragma unroll
  for (int j = 0; j < 8; j++) {
    hi[j] = f2bf(v[j]);
    lo[j] = f2bf(v[j] - bf2f(hi[j]));
  }
}

// ---------------- f32 -> bf16 convert (embed table)
__global__ __launch_bounds__(256) void k_f2bf(const float* __restrict__ in,
                                              u16* __restrict__ out, long n4) {
  long i = (long)blockIdx.x * 256 + threadIdx.x;
  long stride = (long)gridDim.x * 256;
  for (; i < n4; i += stride) {
    float4 v = ((const float4*)in)[i];
    ushort4 o;
    o.x = f2bf(v.x); o.y = f2bf(v.y); o.z = f2bf(v.z); o.w = f2bf(v.w);
    ((ushort4*)out)[i] = o;
  }
}

// ---------------- weight convert + transpose: f32 [nmat][K][N] -> u16 hi/lo [nmat][N][K]
__global__ __launch_bounds__(256) void k_wcvt(const float* __restrict__ src,
    u16* __restrict__ dhi, u16* __restrict__ dlo, int K, int N) {
  __shared__ float t[64][65];
  int bid = blockIdx.x;
  int tn = N >> 6, tk = K >> 6;
  int mat = bid / (tn * tk);
  int rem = bid % (tn * tk);
  int k0 = (rem / tn) << 6;
  int n0 = (rem % tn) << 6;
  const float* s = src + (long)mat * K * N;
  u16* oh = dhi + (long)mat * K * N;
  u16* ol = dlo + (long)mat * K * N;
  int tid = threadIdx.x;
  int r = tid >> 4, c4 = (tid & 15) << 2;
#pragma unroll
  for (int rr = 0; rr < 64; rr += 16) {
    float4 v = *(const float4*)(s + (long)(k0 + r + rr) * N + n0 + c4);
    t[r + rr][c4] = v.x; t[r + rr][c4 + 1] = v.y;
    t[r + rr][c4 + 2] = v.z; t[r + rr][c4 + 3] = v.w;
  }
  __syncthreads();
  int n = tid >> 2, kc = (tid & 3) << 4;
  u16 hi[16], lo[16];
#pragma unroll
  for (int j = 0; j < 16; j++) {
    float v = t[kc + j][n];
    hi[j] = f2bf(v);
    lo[j] = f2bf(v - bf2f(hi[j]));
  }
  u16* po = oh + (long)(n0 + n) * K + k0 + kc;
  *(uint4*)(po) = *(uint4*)hi;
  *(uint4*)(po + 8) = *(uint4*)(hi + 8);
  u16* pl = ol + (long)(n0 + n) * K + k0 + kc;
  *(uint4*)(pl) = *(uint4*)lo;
  *(uint4*)(pl + 8) = *(uint4*)(lo + 8);
}

// ---------------- shared in-register rmsnorm tail
__device__ __forceinline__ void norm_emit_hl(float4 v, const float* __restrict__ w,
    u16* __restrict__ ohi, u16* __restrict__ olo, int t) {
  float ss = v.x * v.x + v.y * v.y + v.z * v.z + v.w * v.w;
  for (int off = 32; off; off >>= 1) ss += __shfl_xor(ss, off);
  __shared__ float red[4];
  if ((threadIdx.x & 63) == 0) red[threadIdx.x >> 6] = ss;
  __syncthreads();
  float tot = red[0] + red[1] + red[2] + red[3];
  float sc = rsqrtf(tot * (1.0f / 1024.0f) + 1e-6f);
  float4 wv = ((const float4*)w)[threadIdx.x];
  float o[4] = {v.x * sc * wv.x, v.y * sc * wv.y, v.z * sc * wv.z, v.w * sc * wv.w};
  ushort4 hi, lo;
  hi.x = f2bf(o[0]); lo.x = f2bf(o[0] - bf2f(hi.x));
  hi.y = f2bf(o[1]); lo.y = f2bf(o[1] - bf2f(hi.y));
  hi.z = f2bf(o[2]); lo.z = f2bf(o[2] - bf2f(hi.z));
  hi.w = f2bf(o[3]); lo.w = f2bf(o[3] - bf2f(hi.w));
  ((ushort4*)(ohi + (long)t * DM))[threadIdx.x] = hi;
  ((ushort4*)(olo + (long)t * DM))[threadIdx.x] = lo;
}
__device__ __forceinline__ void norm_emit_b(float4 v, const float* __restrict__ w,
    u16* __restrict__ out, int t) {
  float ss = v.x * v.x + v.y * v.y + v.z * v.z + v.w * v.w;
  for (int off = 32; off; off >>= 1) ss += __shfl_xor(ss, off);
  __shared__ float red[4];
  if ((threadIdx.x & 63) == 0) red[threadIdx.x >> 6] = ss;
  __syncthreads();
  float tot = red[0] + red[1] + red[2] + red[3];
  float sc = rsqrtf(tot * (1.0f / 1024.0f) + 1e-6f);
  float4 wv = ((const float4*)w)[threadIdx.x];
  ushort4 o;
  o.x = f2bf(v.x * sc * wv.x); o.y = f2bf(v.y * sc * wv.y);
  o.z = f2bf(v.z * sc * wv.z); o.w = f2bf(v.w * sc * wv.w);
  ((ushort4*)(out + (long)t * DM))[threadIdx.x] = o;
}

// ---------------- embedding gather fused with first rmsnorm (+zero counts)
__global__ __launch_bounds__(256) void k_gather_norm(const int* __restrict__ tok,
    const float* __restrict__ embed, const float* __restrict__ w,
    float* __restrict__ x, u16* __restrict__ ohi, u16* __restrict__ olo,
    int* __restrict__ counts) {
  int t = blockIdx.x;
  if (t == 0 && threadIdx.x < NEXP) counts[threadIdx.x] = 0;
  float4 v = ((const float4*)(embed + (long)tok[t] * DM))[threadIdx.x];
  ((float4*)(x + (long)t * DM))[threadIdx.x] = v;
  norm_emit_hl(v, w, ohi, olo, t);
}

// ---------------- MFMA flash attention: reads pre-split qkv hi/lo bf16
#define KP 72
#define VP 40
#define PP 36
__global__ __launch_bounds__(256) void k_attn(const u16* __restrict__ qhi,
    const u16* __restrict__ qlo, u16* __restrict__ chi, u16* __restrict__ clo) {
  __shared__ u16 Ksh[32 * KP], Ksl[32 * KP];
  __shared__ u16 Vsh[64 * VP], Vsl[64 * VP];
  __shared__ float Ps[4][16 * PP];
  int bid = blockIdx.x;
  int xcd = bid & 7, r = bid >> 3;
  int bh = xcd * 4 + (r >> 4);
  int qt = 15 - (r & 15);
  int b = bh >> 4, h = bh & 15;
  int tid = threadIdx.x, w = tid >> 6, lane = tid & 63;
  int lrow = lane & 15, lgrp = lane >> 4;
  int q0 = qt * 64;
  long qrow = (long)(b * SEQ + q0 + w * 16 + lrow);
  bf16x8 qh[2], ql[2];
#pragma unroll
  for (int dsl = 0; dsl < 2; dsl++) {
    long off = qrow * 3072 + h * 64 + dsl * 32 + lgrp * 8;
    qh[dsl] = *(const bf16x8*)(qhi + off);
    ql[dsl] = *(const bf16x8*)(qlo + off);
  }
  f32x4 cacc[4] = {};
  float mst[4], lst[4];
#pragma unroll
  for (int j = 0; j < 4; j++) { mst[j] = -__builtin_inff(); lst[j] = 0.0f; }
  int srow = tid >> 3, dchunk = (tid & 7) * 8;
  for (int s0 = 0; s0 < q0 + 64; s0 += 32) {
    long kvrow = (long)(b * SEQ + s0 + srow) * 3072 + h * 64;
    {
      *(uint4*)(Ksh + srow * KP + dchunk) = *(const uint4*)(qhi + kvrow + 1024 + dchunk);
      *(uint4*)(Ksl + srow * KP + dchunk) = *(const uint4*)(qlo + kvrow + 1024 + dchunk);
      uint4 hv4 = *(const uint4*)(qhi + kvrow + 2048 + dchunk);
      uint4 lv4 = *(const uint4*)(qlo + kvrow + 2048 + dchunk);
      const u16* hp = (const u16*)&hv4;
      const u16* lp = (const u16*)&lv4;
#pragma unroll
      for (int j = 0; j < 8; j++) {
        Vsh[(dchunk + j) * VP + srow] = hp[j];
        Vsl[(dchunk + j) * VP + srow] = lp[j];
      }
    }
    __syncthreads();
    f32x4 sacc[2] = {};
#pragma unroll
    for (int sf = 0; sf < 2; sf++)
#pragma unroll
      for (int dsl = 0; dsl < 2; dsl++) {
        bf16x8 kh = *(const bf16x8*)(Ksh + (sf * 16 + lrow) * KP + dsl * 32 + lgrp * 8);
        bf16x8 kl = *(const bf16x8*)(Ksl + (sf * 16 + lrow) * KP + dsl * 32 + lgrp * 8);
        sacc[sf] = __builtin_amdgcn_mfma_f32_16x16x32_bf16(qh[dsl], kh, sacc[sf], 0, 0, 0);
        sacc[sf] = __builtin_amdgcn_mfma_f32_16x16x32_bf16(qh[dsl], kl, sacc[sf], 0, 0, 0);
        sacc[sf] = __builtin_amdgcn_mfma_f32_16x16x32_bf16(ql[dsl], kh, sacc[sf], 0, 0, 0);
      }
#pragma unroll
    for (int sf = 0; sf < 2; sf++)
#pragma unroll
      for (int j = 0; j < 4; j++) {
        int col = s0 + sf * 16 + lrow;
        int row = q0 + w * 16 + lgrp * 4 + j;
        float v = sacc[sf][j] * 0.125f;
        sacc[sf][j] = (col <= row) ? v : -1e30f;
      }
    float fac[4];
#pragma unroll
    for (int j = 0; j < 4; j++) {
      float mx = fmaxf(sacc[0][j], sacc[1][j]);
      for (int off = 1; off < 16; off <<= 1) mx = fmaxf(mx, __shfl_xor(mx, off));
      float mnew = fmaxf(mst[j], mx);
      float f = __expf(mst[j] - mnew);
      mst[j] = mnew;
      float p0 = __expf(sacc[0][j] - mnew);
      float p1 = __expf(sacc[1][j] - mnew);
      sacc[0][j] = p0; sacc[1][j] = p1;
      float ps = p0 + p1;
      for (int off = 1; off < 16; off <<= 1) ps += __shfl_xor(ps, off);
      lst[j] = lst[j] * f + ps;
      fac[j] = f;
    }
#pragma unroll
    for (int n = 0; n < 4; n++)
#pragma unroll
      for (int j = 0; j < 4; j++) cacc[n][j] *= fac[j];
#pragma unroll
    for (int sf = 0; sf < 2; sf++)
#pragma unroll
      for (int j = 0; j < 4; j++)
        Ps[w][(lgrp * 4 + j) * PP + sf * 16 + lrow] = sacc[sf][j];
    float pv[8];
#pragma unroll
    for (int j = 0; j < 8; j++) pv[j] = Ps[w][lrow * PP + lgrp * 8 + j];
    u16 phi[8], plo[8];
    split8(pv, phi, plo);
    bf16x8 ph = *(bf16x8*)phi, pl = *(bf16x8*)plo;
#pragma unroll
    for (int n = 0; n < 4; n++) {
      bf16x8 vh = *(const bf16x8*)(Vsh + (n * 16 + lrow) * VP + lgrp * 8);
      bf16x8 vl = *(const bf16x8*)(Vsl + (n * 16 + lrow) * VP + lgrp * 8);
      cacc[n] = __builtin_amdgcn_mfma_f32_16x16x32_bf16(ph, vh, cacc[n], 0, 0, 0);
      cacc[n] = __builtin_amdgcn_mfma_f32_16x16x32_bf16(ph, vl, cacc[n], 0, 0, 0);
      cacc[n] = __builtin_amdgcn_mfma_f32_16x16x32_bf16(pl, vh, cacc[n], 0, 0, 0);
    }
    __syncthreads();
  }
#pragma unroll
  for (int n = 0; n < 4; n++)
#pragma unroll
    for (int j = 0; j < 4; j++) {
      long t = (long)(b * SEQ + q0 + w * 16 + lgrp * 4 + j);
      float v = cacc[n][j] / lst[j];
      u16 hv = f2bf(v);
      chi[t * DM + h * 64 + n * 16 + lrow] = hv;
      clo[t * DM + h * 64 + n * 16 + lrow] = f2bf(v - bf2f(hv));
    }
}

// ======== shared GEMM machinery ====

// copy-stage 128 rows x 32 k of pre-split u16 [rows][ldk]
__device__ __forceinline__ void stageA_cp(const u16* __restrict__ Ahi,
    const u16* __restrict__ Alo, long ldk, long m0, int k0,
    u16* Ah, u16* Al, int tid, int split) {
#pragma unroll
  for (int ph = 0; ph < 2; ph++) {
    int c = tid + 256 * ph;
    int row = c >> 2, kc = c & 3;
    long off = (m0 + row) * ldk + k0 + kc * 8;
    *(uint4*)(Ah + row * APAD + kc * 8) = *(const uint4*)(Ahi + off);
    if (split) *(uint4*)(Al + row * APAD + kc * 8) = *(const uint4*)(Alo + off);
  }
}

// transpose-convert stage of f32 [k][n] weights (k_w2 only)
__device__ __forceinline__ void stageB_tr(const float* __restrict__ B, int ldb,
    int k0, int n0, u16* Bh, u16* Bl, int tid, int split) {
#pragma unroll
  for (int ph = 0; ph < 2; ph++) {
    int c = tid + 256 * ph;
    int nr = c & 127;
    int ks = c >> 7;
    const float* src = B + (long)(k0 + ks * 8) * ldb + n0 + nr;
    float v[8];
#pragma unroll
    for (int j = 0; j < 8; j++) v[j] = src[(long)j * ldb];
    u16 hi[8];
#pragma unroll
    for (int j = 0; j < 8; j++) hi[j] = f2bf(v[j]);
    *(uint4*)(Bh + nr * APAD + ks * 8) = *(uint4*)hi;
    if (split) {
      u16 lo[8];
#pragma unroll
      for (int j = 0; j < 8; j++) lo[j] = f2bf(v[j] - bf2f(hi[j]));
      *(uint4*)(Bl + nr * APAD + ks * 8) = *(uint4*)lo;
    }
  }
}

// ---------------- wo projection: 64x128 tile, grid 256, pre-split B
__global__ __launch_bounds__(256) void k_wo(
    const u16* __restrict__ Ahi, const u16* __restrict__ Alo,
    const u16* __restrict__ Bth, const u16* __restrict__ Btl,
    float* __restrict__ C) {
  __shared__ u16 Ah[64 * APAD], Al[64 * APAD], Bh[128 * APAD], Bl[128 * APAD];
  int bid = blockIdx.x;
  int n0 = (bid & 7) * 128;
  int m0 = (bid >> 3) * 64;
  int tid = threadIdx.x, lane = tid & 63, w = tid >> 6;
  int wr = w >> 1, wc = w & 1, lrow = lane & 15, lgrp = lane >> 4;
  f32x4 acc[2][4] = {};
  for (int k0 = 0; k0 < 1024; k0 += 32) {
    {
      int row = tid >> 2, kc = tid & 3;
      long off = (long)(m0 + row) * DM + k0 + kc * 8;
      *(uint4*)(Ah + row * APAD + kc * 8) = *(const uint4*)(Ahi + off);
      *(uint4*)(Al + row * APAD + kc * 8) = *(const uint4*)(Alo + off);
    }
    stageA_cp(Bth, Btl, 1024, n0, k0, Bh, Bl, tid, 1);
    __syncthreads();
    bf16x8 ah[2], al[2], bh[4], bl[4];
#pragma unroll
    for (int i = 0; i < 2; i++) {
      ah[i] = *(const bf16x8*)(Ah + (wr * 32 + i * 16 + lrow) * APAD + lgrp * 8);
      al[i] = *(const bf16x8*)(Al + (wr * 32 + i * 16 + lrow) * APAD + lgrp * 8);
    }
#pragma unroll
    for (int j = 0; j < 4; j++) {
      bh[j] = *(const bf16x8*)(Bh + (wc * 64 + j * 16 + lrow) * APAD + lgrp * 8);
      bl[j] = *(const bf16x8*)(Bl + (wc * 64 + j * 16 + lrow) * APAD + lgrp * 8);
    }
#pragma unroll
    for (int i = 0; i < 2; i++)
#pragma unroll
      for (int j = 0; j < 4; j++) {
        acc[i][j] = __builtin_amdgcn_mfma_f32_16x16x32_bf16(ah[i], bh[j], acc[i][j], 0, 0, 0);
        acc[i][j] = __builtin_amdgcn_mfma_f32_16x16x32_bf16(ah[i], bl[j], acc[i][j], 0, 0, 0);
        acc[i][j] = __builtin_amdgcn_mfma_f32_16x16x32_bf16(al[i], bh[j], acc[i][j], 0, 0, 0);
      }
    __syncthreads();
  }
#pragma unroll
  for (int i = 0; i < 2; i++)
#pragma unroll
    for (int j = 0; j < 4; j++) {
      int col = n0 + wc * 64 + j * 16 + lrow;
#pragma unroll
      for (int jj = 0; jj < 4; jj++) {
        int r = m0 + wr * 32 + i * 16 + lgrp * 4 + jj;
        C[(long)r * DM + col] += acc[i][j][jj];
      }
    }
}

// ---------------- fused QKV + RoPE: 64x128 tile, grid 768, pre-split B
__global__ __launch_bounds__(256) void k_gemm_qkv(
    const u16* __restrict__ Ahi, const u16* __restrict__ Alo,
    const u16* __restrict__ Bqh, const u16* __restrict__ Bql,
    const u16* __restrict__ Bkh, const u16* __restrict__ Bkl,
    const u16* __restrict__ Bvh, const u16* __restrict__ Bvl,
    u16* __restrict__ Chi, u16* __restrict__ Clo) {
  __shared__ u16 Ah[64 * APAD], Al[64 * APAD], Bh[128 * APAD], Bl[128 * APAD];
  int bid = blockIdx.x;
  int xcd = bid & 7, r = bid >> 3;
  int nb = xcd * 3 + r / 32;
  int m0 = (r & 31) * 64;
  const u16* Bth = (nb < 8) ? Bqh : (nb < 16) ? Bkh : Bvh;
  const u16* Btl = (nb < 8) ? Bql : (nb < 16) ? Bkl : Bvl;
  int bn0 = (nb & 7) * 128;
  int tid = threadIdx.x, lane = tid & 63, w = tid >> 6;
  int wr = w >> 1, wc = w & 1, lrow = lane & 15, lgrp = lane >> 4;
  f32x4 acc[2][4] = {};
  for (int k0 = 0; k0 < 1024; k0 += 32) {
    {
      int row = tid >> 2, kc = tid & 3;
      long off = (long)(m0 + row) * DM + k0 + kc * 8;
      *(uint4*)(Ah + row * APAD + kc * 8) = *(const uint4*)(Ahi + off);
      *(uint4*)(Al + row * APAD + kc * 8) = *(const uint4*)(Alo + off);
    }
    stageA_cp(Bth, Btl, 1024, bn0, k0, Bh, Bl, tid, 1);
    __syncthreads();
    bf16x8 ah[2], al[2], bh[4], bl[4];
#pragma unroll
    for (int i = 0; i < 2; i++) {
      ah[i] = *(const bf16x8*)(Ah + (wr * 32 + i * 16 + lrow) * APAD + lgrp * 8);
      al[i] = *(const bf16x8*)(Al + (wr * 32 + i * 16 + lrow) * APAD + lgrp * 8);
    }
#pragma unroll
    for (int j = 0; j < 4; j++) {
      bh[j] = *(const bf16x8*)(Bh + (wc * 64 + j * 16 + lrow) * APAD + lgrp * 8);
      bl[j] = *(const bf16x8*)(Bl + (wc * 64 + j * 16 + lrow) * APAD + lgrp * 8);
    }
#pragma unroll
    for (int i = 0; i < 2; i++)
#pragma unroll
      for (int j = 0; j < 4; j++) {
        acc[i][j] = __builtin_amdgcn_mfma_f32_16x16x32_bf16(ah[i], bh[j], acc[i][j], 0, 0, 0);
        acc[i][j] = __builtin_amdgcn_mfma_f32_16x16x32_bf16(ah[i], bl[j], acc[i][j], 0, 0, 0);
        acc[i][j] = __builtin_amdgcn_mfma_f32_16x16x32_bf16(al[i], bh[j], acc[i][j], 0, 0, 0);
      }
    __syncthreads();
  }
  if (nb < 16) {
    float inv1 = exp2f((float)lrow * (-13.287712379549449f / 32.0f));
    float inv2 = exp2f((float)(lrow + 16) * (-13.287712379549449f / 32.0f));
#pragma unroll
    for (int i = 0; i < 2; i++)
#pragma unroll
      for (int jj = 0; jj < 4; jj++) {
        int rr = m0 + wr * 32 + i * 16 + lgrp * 4 + jj;
        float s = (float)(rr & (SEQ - 1));
        float sn1, cs1, sn2, cs2;
        sincosf(s * inv1, &sn1, &cs1);
        sincosf(s * inv2, &sn2, &cs2);
        float q1 = acc[i][0][jj], q2 = acc[i][2][jj];
        acc[i][0][jj] = q1 * cs1 - q2 * sn1;
        acc[i][2][jj] = q1 * sn1 + q2 * cs1;
        float p1 = acc[i][1][jj], p2 = acc[i][3][jj];
        acc[i][1][jj] = p1 * cs2 - p2 * sn2;
        acc[i][3][jj] = p1 * sn2 + p2 * cs2;
      }
  }
#pragma unroll
  for (int i = 0; i < 2; i++)
#pragma unroll
    for (int j = 0; j < 4; j++) {
      int col = nb * 128 + wc * 64 + j * 16 + lrow;
#pragma unroll
      for (int jj = 0; jj < 4; jj++) {
        int rr = m0 + wr * 32 + i * 16 + lgrp * 4 + jj;
        float v = acc[i][j][jj];
        u16 hv = f2bf(v);
        Chi[(long)rr * 3072 + col] = hv;
        Clo[(long)rr * 3072 + col] = f2bf(v - bf2f(hv));
      }
    }
}

// ---------------- fused MoE up-projection + silu, pre-split transposed W1/W3
template <int SPLIT>
__global__ __launch_bounds__(256) void k_w13(
    const u16* __restrict__ Ahi, const u16* __restrict__ Alo,
    const u16* __restrict__ W1h, const u16* __restrict__ W1l,
    const u16* __restrict__ W3h, const u16* __restrict__ W3l,
    const int* __restrict__ lists, const int* __restrict__ counts,
    const int* __restrict__ aoff,
    u16* __restrict__ hhi, u16* __restrict__ hlo) {
  int bid = blockIdx.x;
  int xcd = bid & 7, r = bid >> 3;      // r 0..159
  int nb = xcd * 2 + r / 80;            // 2 n-panels per XCD (0..15)
  int m0 = (r % 80) * 64;               // m fastest (80 panels of 64)
  int e = -1;
#pragma unroll
  for (int i = 0; i < NEXP; i++)
    if (m0 >= aoff[i] && m0 < aoff[i + 1]) e = i;
  if (e < 0) return;
  int lr0 = m0 - aoff[e];
  int Mc = counts[e];
  if (lr0 >= Mc) return;
  long eoff = (size_t)e * 2048 * 1024;
  int bn0 = nb * 128;
  const int* lst = lists + e * TOK;
  __shared__ u16 Ah[64 * APAD], B1h[128 * APAD], B3h[128 * APAD];
  __shared__ u16 Al[SPLIT ? 64 * APAD : 1];
  __shared__ u16 B1l[SPLIT ? 128 * APAD : 1], B3l[SPLIT ? 128 * APAD : 1];
  int tid = threadIdx.x, lane = tid & 63, w = tid >> 6;
  int wr = w >> 1, wc = w & 1, lrow = lane & 15, lgrp = lane >> 4;
  f32x4 acc1[2][4] = {}, acc3[2][4] = {};
  for (int k0 = 0; k0 < 1024; k0 += 32) {
    {  // A: 64 gathered rows, single pass, shared by both GEMMs
      int row = tid >> 2, kc = tid & 3;
      uint4 vh = make_uint4(0, 0, 0, 0), vl = make_uint4(0, 0, 0, 0);
      if (lr0 + row < Mc) {
        long off = (long)lst[lr0 + row] * DM + k0 + kc * 8;
        vh = *(const uint4*)(Ahi + off);
        if (SPLIT) vl = *(const uint4*)(Alo + off);
      }
      *(uint4*)(Ah + row * APAD + kc * 8) = vh;
      if (SPLIT) *(uint4*)(Al + row * APAD + kc * 8) = vl;
    }
    stageA_cp(W1h + eoff, W1l + eoff, 1024, bn0, k0, B1h, B1l, tid, SPLIT);
    stageA_cp(W3h + eoff, W3l + eoff, 1024, bn0, k0, B3h, B3l, tid, SPLIT);
    __syncthreads();
    bf16x8 ah[2], al[2];
#pragma unroll
    for (int i = 0; i < 2; i++) {
      ah[i] = *(const bf16x8*)(Ah + (wr * 32 + i * 16 + lrow) * APAD + lgrp * 8);
      if (SPLIT) al[i] = *(const bf16x8*)(Al + (wr * 32 + i * 16 + lrow) * APAD + lgrp * 8);
    }
    {  // gate = A @ W1
      bf16x8 bh[4];
#pragma unroll
      for (int j = 0; j < 4; j++)
        bh[j] = *(const bf16x8*)(B1h + (wc * 64 + j * 16 + lrow) * APAD + lgrp * 8);
#pragma unroll
      for (int i = 0; i < 2; i++)
#pragma unroll
        for (int j = 0; j < 4; j++)
          acc1[i][j] = __builtin_amdgcn_mfma_f32_16x16x32_bf16(ah[i], bh[j], acc1[i][j], 0, 0, 0);
      if (SPLIT) {
        bf16x8 bl[4];
#pragma unroll
        for (int j = 0; j < 4; j++)
          bl[j] = *(const bf16x8*)(B1l + (wc * 64 + j * 16 + lrow) * APAD + lgrp * 8);
#pragma unroll
        for (int i = 0; i < 2; i++)
#pragma unroll
          for (int j = 0; j < 4; j++) {
            acc1[i][j] = __builtin_amdgcn_mfma_f32_16x16x32_bf16(ah[i], bl[j], acc1[i][j], 0, 0, 0);
            acc1[i][j] = __builtin_amdgcn_mfma_f32_16x16x32_bf16(al[i], bh[j], acc1[i][j], 0, 0, 0);
          }
      }
    }
    {  // up = A @ W3
      bf16x8 bh[4];
#pragma unroll
      for (int j = 0; j < 4; j++)
        bh[j] = *(const bf16x8*)(B3h + (wc * 64 + j * 16 + lrow) * APAD + lgrp * 8);
#pragma unroll
      for (int i = 0; i < 2; i++)
#pragma unroll
        for (int j = 0; j < 4; j++)
          acc3[i][j] = __builtin_amdgcn_mfma_f32_16x16x32_bf16(ah[i], bh[j], acc3[i][j], 0, 0, 0);
      if (SPLIT) {
        bf16x8 bl[4];
#pragma unroll
        for (int j = 0; j < 4; j++)
          bl[j] = *(const bf16x8*)(B3l + (wc * 64 + j * 16 + lrow) * APAD + lgrp * 8);
#pragma unroll
        for (int i = 0; i < 2; i++)
#pragma unroll
          for (int j = 0; j < 4; j++) {
            acc3[i][j] = __builtin_amdgcn_mfma_f32_16x16x32_bf16(ah[i], bl[j], acc3[i][j], 0, 0, 0);
            acc3[i][j] = __builtin_amdgcn_mfma_f32_16x16x32_bf16(al[i], bh[j], acc3[i][j], 0, 0, 0);
          }
      }
    }
    __syncthreads();
  }
#pragma unroll
  for (int i = 0; i < 2; i++)
#pragma unroll
    for (int j = 0; j < 4; j++) {
      int col = bn0 + wc * 64 + j * 16 + lrow;
#pragma unroll
      for (int jj = 0; jj < 4; jj++) {
        int rl = wr * 32 + i * 16 + lgrp * 4 + jj;
        if (lr0 + rl >= Mc) continue;
        float g = acc1[i][j][jj], u = acc3[i][j][jj];
        float o = g / (1.0f + __expf(-g)) * u;
        u16 hv = f2bf(o);
        hhi[(long)(m0 + rl) * 2048 + col] = hv;
        if (SPLIT) hlo[(long)(m0 + rl) * 2048 + col] = f2bf(o - bf2f(hv));
      }
    }
}

// ---------------- batched MoE down-projection: 64x128 tile, grid 640 (f32 W2)
template <int SPLIT>
__global__ __launch_bounds__(256) void k_w2(
    const u16* __restrict__ Ahi, const u16* __restrict__ Alo,
    const float* __restrict__ W2,
    const int* __restrict__ counts, const int* __restrict__ aoff,
    float* __restrict__ y) {
  int bid = blockIdx.x;
  int n0 = (bid & 7) * 128;
  int m0 = (bid >> 3) * 64;
  int e = -1;
#pragma unroll
  for (int i = 0; i < NEXP; i++)
    if (m0 >= aoff[i] && m0 < aoff[i + 1]) e = i;
  if (e < 0) return;
  int lr0 = m0 - aoff[e];
  int Mc = counts[e];
  if (lr0 >= Mc) return;
  const float* B = W2 + (size_t)e * 2048 * 1024;
  __shared__ u16 Ah[64 * APAD], Bh[128 * APAD];
  __shared__ u16 Al[SPLIT ? 64 * APAD : 1], Bl[SPLIT ? 128 * APAD : 1];
  int tid = threadIdx.x, lane = tid & 63, w = tid >> 6;
  int wr = w >> 1, wc = w & 1, lrow = lane & 15, lgrp = lane >> 4;
  f32x4 acc[2][4] = {};
  for (int k0 = 0; k0 < 2048; k0 += 32) {
    {
      int row = tid >> 2, kc = tid & 3;
      long off = (long)(m0 + row) * 2048 + k0 + kc * 8;
      *(uint4*)(Ah + row * APAD + kc * 8) = *(const uint4*)(Ahi + off);
      if (SPLIT) *(uint4*)(Al + row * APAD + kc * 8) = *(const uint4*)(Alo + off);
    }
    stageB_tr(B, 1024, k0, n0, Bh, Bl, tid, SPLIT);
    __syncthreads();
    bf16x8 ah[2], bh[4];
#pragma unroll
    for (int i = 0; i < 2; i++)
      ah[i] = *(const bf16x8*)(Ah + (wr * 32 + i * 16 + lrow) * APAD + lgrp * 8);
#pragma unroll
    for (int j = 0; j < 4; j++)
      bh[j] = *(const bf16x8*)(Bh + (wc * 64 + j * 16 + lrow) * APAD + lgrp * 8);
#pragma unroll
    for (int i = 0; i < 2; i++)
#pragma unroll
      for (int j = 0; j < 4; j++)
        acc[i][j] = __builtin_amdgcn_mfma_f32_16x16x32_bf16(ah[i], bh[j], acc[i][j], 0, 0, 0);
    if (SPLIT) {
      bf16x8 al[2], bl[4];
#pragma unroll
      for (int i = 0; i < 2; i++)
        al[i] = *(const bf16x8*)(Al + (wr * 32 + i * 16 + lrow) * APAD + lgrp * 8);
#pragma unroll
      for (int j = 0; j < 4; j++)
        bl[j] = *(const bf16x8*)(Bl + (wc * 64 + j * 16 + lrow) * APAD + lgrp * 8);
#pragma unroll
      for (int i = 0; i < 2; i++)
#pragma unroll
        for (int j = 0; j < 4; j++) {
          acc[i][j] = __builtin_amdgcn_mfma_f32_16x16x32_bf16(ah[i], bl[j], acc[i][j], 0, 0, 0);
          acc[i][j] = __builtin_amdgcn_mfma_f32_16x16x32_bf16(al[i], bh[j], acc[i][j], 0, 0, 0);
        }
    }
    __syncthreads();
  }
#pragma unroll
  for (int i = 0; i < 2; i++)
#pragma unroll
    for (int j = 0; j < 4; j++) {
      int col = n0 + wc * 64 + j * 16 + lrow;
#pragma unroll
      for (int jj = 0; jj < 4; jj++) {
        int rl = wr * 32 + i * 16 + lgrp * 4 + jj;
        if (lr0 + rl >= Mc) continue;
        y[(long)(m0 + rl) * DM + col] = acc[i][j][jj];
      }
    }
}

// ---------------- combine + next-layer norm fused (+zero counts when !FINAL)
template <int FINAL>
__global__ __launch_bounds__(256) void k_combine_norm(const float* __restrict__ y,
    const int* __restrict__ aoff, const int* __restrict__ tok_e,
    const int* __restrict__ tok_pos, const float* __restrict__ tok_gate,
    float* __restrict__ x, const float* __restrict__ wnext,
    u16* __restrict__ ohi, u16* __restrict__ olo, int* __restrict__ counts) {
  int t = blockIdx.x;
  if (!FINAL && t == 0 && threadIdx.x < NEXP) counts[threadIdx.x] = 0;
  float4 acc = ((float4*)(x + (long)t * DM))[threadIdx.x];
#pragma unroll
  for (int j = 0; j < 2; j++) {
    int e = tok_e[t * 2 + j];
    long g = aoff[e] + tok_pos[t * 2 + j];
    float gt = tok_gate[t * 2 + j];
    float4 yv = ((const float4*)(y + g * DM))[threadIdx.x];
    acc.x += gt * yv.x; acc.y += gt * yv.y;
    acc.z += gt * yv.z; acc.w += gt * yv.w;
  }
  ((float4*)(x + (long)t * DM))[threadIdx.x] = acc;
  if (FINAL) norm_emit_b(acc, wnext, ohi, t);
  else norm_emit_hl(acc, wnext, ohi, olo, t);
}

// ---------------- logits fragment compute
__device__ __forceinline__ void logits_mma(const u16* As, const u16* Bs,
    f32x4 (&acc)[4][4], int wr, int wc, int lrow, int lgrp) {
  bf16x8 af[4], bfr[4];
#pragma unroll
  for (int i = 0; i < 4; i++) {
    af[i] = *(const bf16x8*)(As + (wr * 64 + i * 16 + lrow) * APAD + lgrp * 8);
    bfr[i] = *(const bf16x8*)(Bs + (wc * 64 + i * 16 + lrow) * APAD + lgrp * 8);
  }
#pragma unroll
  for (int i = 0; i < 4; i++)
#pragma unroll
    for (int j = 0; j < 4; j++)
      acc[i][j] = __builtin_amdgcn_mfma_f32_16x16x32_bf16(af[i], bfr[j], acc[i][j], 0, 0, 0);
}

// ---------------- logits GEMM (r14 structure, measured 188-194 us)
__global__ __launch_bounds__(512) void k_logits(
    const u16* __restrict__ A, const u16* __restrict__ Bt,
    float* __restrict__ C) {
  __shared__ u16 AsA[256 * APAD], BsA[128 * APAD];
  __shared__ u16 AsB[256 * APAD], BsB[128 * APAD];
  int bid = blockIdx.x;
  int xcd = bid & 7, rank = bid >> 3;
  int bx = xcd * 32 + (rank >> 3);
  int by = rank & 7;
  if (bx >= VOCAB / 128) return;
  int m0 = by * 256, n0 = bx * 128;
  int tid = threadIdx.x, lane = tid & 63, w = tid >> 6;
  int wr = w >> 1, wc = w & 1;
  int lrow = lane & 15, lgrp = lane >> 4;
  int arow = tid >> 2, akc = tid & 3;
  f32x4 acc[4][4] = {};
  const u16* Ap = A + (long)(m0 + arow) * 1024 + akc * 8;
  const u16* Ap2 = A + (long)(m0 + arow + 128) * 1024 + akc * 8;
  const u16* Bp = Bt + (long)(n0 + arow) * 1024 + akc * 8;
  uint4 a0 = *(const uint4*)(Ap);
  uint4 a1 = *(const uint4*)(Ap2);
  uint4 b0 = *(const uint4*)(Bp);
  *(uint4*)(AsA + arow * APAD + akc * 8) = a0;
  *(uint4*)(AsA + (arow + 128) * APAD + akc * 8) = a1;
  *(uint4*)(BsA + arow * APAD + akc * 8) = b0;
  __syncthreads();
  for (int kt = 0; kt < 32; kt += 2) {
    {
      int k0 = (kt + 1) * 32;
      a0 = *(const uint4*)(Ap + k0);
      a1 = *(const uint4*)(Ap2 + k0);
      b0 = *(const uint4*)(Bp + k0);
    }
    logits_mma(AsA, BsA, acc, wr, wc, lrow, lgrp);
    *(uint4*)(AsB + arow * APAD + akc * 8) = a0;
    *(uint4*)(AsB + (arow + 128) * APAD + akc * 8) = a1;
    *(uint4*)(BsB + arow * APAD + akc * 8) = b0;
    __syncthreads();
    if (kt + 2 < 32) {
      int k0 = (kt + 2) * 32;
      a0 = *(const uint4*)(Ap + k0);
      a1 = *(const uint4*)(Ap2 + k0);
      b0 = *(const uint4*)(Bp + k0);
    }
    logits_mma(AsB, BsB, acc, wr, wc, lrow, lgrp);
    if (kt + 2 < 32) {
      *(uint4*)(AsA + arow * APAD + akc * 8) = a0;
      *(uint4*)(AsA + (arow + 128) * APAD + akc * 8) = a1;
      *(uint4*)(BsA + arow * APAD + akc * 8) = b0;
    }
    __syncthreads();
  }
#pragma unroll
  for (int i = 0; i < 4; i++)
#pragma unroll
    for (int j = 0; j < 4; j++) {
      int col = n0 + wc * 64 + j * 16 + lrow;
#pragma unroll
      for (int jj = 0; jj < 4; jj++) {
        int r = m0 + wr * 64 + i * 16 + lgrp * 4 + jj;
        C[(long)r * VOCAB + col] = acc[i][j][jj];
      }
    }
}

// ---------------- router fused with moe rmsnorm: top-2 + emit xn hi/lo
__global__ __launch_bounds__(256) void k_router_norm(const float* __restrict__ x,
    const float* __restrict__ nw, const float* __restrict__ rw,
    int* __restrict__ counts, int* __restrict__ lists,
    int* __restrict__ tok_e, int* __restrict__ tok_pos,
    float* __restrict__ tok_gate,
    u16* __restrict__ ohi, u16* __restrict__ olo) {
  int t = blockIdx.x * 4 + (threadIdx.x >> 6);
  int lane = threadIdx.x & 63;
  const float* xr = x + (long)t * DM;
  float xv[16], wv[16];
  float ss = 0.0f;
  float p[8] = {0, 0, 0, 0, 0, 0, 0, 0};
#pragma unroll
  for (int i = 0; i < 16; i++) {
    int d = lane + 64 * i;
    xv[i] = xr[d];
    wv[i] = nw[d];
    ss += xv[i] * xv[i];
    float xw = xv[i] * wv[i];
#pragma unroll
    for (int e = 0; e < 8; e++) p[e] += xw * rw[e * DM + d];
  }
  for (int off = 32; off; off >>= 1) ss += __shfl_xor(ss, off);
#pragma unroll
  for (int e = 0; e < 8; e++)
    for (int off = 32; off; off >>= 1) p[e] += __shfl_xor(p[e], off);
  float sc = rsqrtf(ss * (1.0f / 1024.0f) + 1e-6f);
#pragma unroll
  for (int i = 0; i < 16; i++) {
    int d = lane + 64 * i;
    float o = xv[i] * sc * wv[i];
    u16 h = f2bf(o);
    ohi[(long)t * DM + d] = h;
    olo[(long)t * DM + d] = f2bf(o - bf2f(h));
  }
  if (lane == 0) {
    int e0 = 0, e1 = -1;
    float v0 = -__builtin_inff(), v1 = -__builtin_inff();
    for (int e = 0; e < 8; e++) {
      float pe = p[e] * sc;
      if (pe > v0) { v1 = v0; e1 = e0; v0 = pe; e0 = e; }
      else if (pe > v1) { v1 = pe; e1 = e; }
    }
    float w0 = 1.0f / (1.0f + expf(v1 - v0));
    int pos0 = atomicAdd(&counts[e0], 1);
    lists[e0 * TOK + pos0] = t;
    tok_e[t * 2] = e0; tok_pos[t * 2] = pos0; tok_gate[t * 2] = w0;
    int pos1 = atomicAdd(&counts[e1], 1);
    lists[e1 * TOK + pos1] = t;
    tok_e[t * 2 + 1] = e1; tok_pos[t * 2 + 1] = pos1; tok_gate[t * 2 + 1] = 1.0f - w0;
  }
}

// ---------------- 64-aligned exclusive prefix of counts
__global__ void k_offsets(const int* __restrict__ counts, int* __restrict__ aoff) {
  if (threadIdx.x == 0 && blockIdx.x == 0) {
    int a = 0;
    for (int e = 0; e < NEXP; e++) {
      aoff[e] = a;
      a += (counts[e] + 63) & ~63;
    }
    aoff[NEXP] = a;
  }
}

extern "C" void kernel_launch(void* const* d_in, const int* in_sizes, int n_in,
                              void* d_out, int out_size, void* d_ws, size_t ws_size,
                              hipStream_t stream) {
  (void)in_sizes; (void)n_in; (void)out_size; (void)ws_size;
  const int* tokens = (const int*)d_in[0];
  const float* embed = (const float*)d_in[1];
  const float* attn_nw = (const float*)d_in[2];
  const float* wq = (const float*)d_in[3];
  const float* wk = (const float*)d_in[4];
  const float* wv = (const float*)d_in[5];
  const float* wo = (const float*)d_in[6];
  const float* moe_nw = (const float*)d_in[7];
  const float* rw = (const float*)d_in[8];
  const float* w1 = (const float*)d_in[9];
  const float* w2 = (const float*)d_in[10];
  const float* w3 = (const float*)d_in[11];
  const float* fin_nw = (const float*)d_in[12];
  float* out = (float*)d_out;

  // ---- scratch carved from d_out (262 MB; all dead before final logits GEMM)
  char* ob = (char*)d_out;
  auto carve = [&](size_t bytes) { char* r = ob; ob += (bytes + 255) & ~(size_t)255; return r; };
  u16*   qkv_hi = (u16*)carve((size_t)TOK * 3072 * 2);
  u16*   qkv_lo = (u16*)carve((size_t)TOK * 3072 * 2);
  u16*   ctx_hi = (u16*)carve((size_t)TOK * DM * 2);
  u16*   ctx_lo = (u16*)carve((size_t)TOK * DM * 2);
  float* x      = (float*)carve((size_t)TOK * DM * 4);
  u16*   hb_hi  = (u16*)carve((size_t)SLOTS * 2048 * 2);
  u16*   hb_lo  = (u16*)carve((size_t)SLOTS * 2048 * 2);
  float* y      = (float*)carve((size_t)SLOTS * 1024 * 4);
  // pre-converted transposed weights (per layer, rewritten each layer)
  u16*   w1t_hi = (u16*)carve((size_t)NEXP * 2048 * 1024 * 2);   // 33.5 MB
  u16*   w1t_lo = (u16*)carve((size_t)NEXP * 2048 * 1024 * 2);
  u16*   w3t_hi = (u16*)carve((size_t)NEXP * 2048 * 1024 * 2);
  u16*   w3t_lo = (u16*)carve((size_t)NEXP * 2048 * 1024 * 2);
  u16*   wqt_hi = (u16*)carve((size_t)DM * DM * 2);              // 2.1 MB each
  u16*   wqt_lo = (u16*)carve((size_t)DM * DM * 2);
  u16*   wkt_hi = (u16*)carve((size_t)DM * DM * 2);
  u16*   wkt_lo = (u16*)carve((size_t)DM * DM * 2);
  u16*   wvt_hi = (u16*)carve((size_t)DM * DM * 2);
  u16*   wvt_lo = (u16*)carve((size_t)DM * DM * 2);
  u16*   wot_hi = (u16*)carve((size_t)DM * DM * 2);
  u16*   wot_lo = (u16*)carve((size_t)DM * DM * 2);
  int*   counts  = (int*)carve(NEXP * 4);
  int*   aoff    = (int*)carve((NEXP + 1) * 4);
  int*   lists   = (int*)carve((size_t)NEXP * TOK * 4);
  int*   tok_e   = (int*)carve((size_t)TOK * 2 * 4);
  int*   tok_pos = (int*)carve((size_t)TOK * 2 * 4);
  float* tok_gate= (float*)carve((size_t)TOK * 2 * 4);
  // ---- d_ws: buffers the final GEMM reads while d_out is being written
  char* wp = (char*)d_ws;
  auto wcarve = [&](size_t bytes) { char* r = wp; wp += (bytes + 255) & ~(size_t)255; return r; };
  u16* xn_hi = (u16*)wcarve((size_t)TOK * DM * 2);
  u16* xn_lo = (u16*)wcarve((size_t)TOK * DM * 2);
  u16* xnb   = (u16*)wcarve((size_t)TOK * DM * 2);
  u16* embB  = (u16*)wcarve((size_t)VOCAB * DM * 2);

  k_f2bf<<<4096, 256, 0, stream>>>(embed, embB, (long)VOCAB * DM / 4);
  k_gather_norm<<<TOK, 256, 0, stream>>>(tokens, embed, attn_nw, x, xn_hi, xn_lo, counts);

  for (int l = 0; l < NL; l++) {
    // pre-convert + transpose this layer's weights (bit-identical hi/lo split)
    k_wcvt<<<256, 256, 0, stream>>>(wq + (size_t)l * DM * DM, wqt_hi, wqt_lo, 1024, 1024);
    k_wcvt<<<256, 256, 0, stream>>>(wk + (size_t)l * DM * DM, wkt_hi, wkt_lo, 1024, 1024);
    k_wcvt<<<256, 256, 0, stream>>>(wv + (size_t)l * DM * DM, wvt_hi, wvt_lo, 1024, 1024);
    k_wcvt<<<256, 256, 0, stream>>>(wo + (size_t)l * DM * DM, wot_hi, wot_lo, 1024, 1024);
    k_wcvt<<<4096, 256, 0, stream>>>(w1 + (size_t)l * NEXP * DM * 2048, w1t_hi, w1t_lo, 1024, 2048);
    k_wcvt<<<4096, 256, 0, stream>>>(w3 + (size_t)l * NEXP * DM * 2048, w3t_hi, w3t_lo, 1024, 2048);

    k_gemm_qkv<<<768, 256, 0, stream>>>(xn_hi, xn_lo,
        wqt_hi, wqt_lo, wkt_hi, wkt_lo, wvt_hi, wvt_lo, qkv_hi, qkv_lo);
    k_attn<<<512, 256, 0, stream>>>(qkv_hi, qkv_lo, ctx_hi, ctx_lo);
    k_wo<<<256, 256, 0, stream>>>(ctx_hi, ctx_lo, wot_hi, wot_lo, x);

    k_router_norm<<<TOK / 4, 256, 0, stream>>>(x, moe_nw + (size_t)l * DM,
        rw + (size_t)l * NEXP * DM, counts, lists, tok_e, tok_pos, tok_gate,
        xn_hi, xn_lo);
    k_offsets<<<1, 64, 0, stream>>>(counts, aoff);
    if (l < NL - 1) {
      k_w13<1><<<1280, 256, 0, stream>>>(xn_hi, xn_lo,
          w1t_hi, w1t_lo, w3t_hi, w3t_lo,
          lists, counts, aoff, hb_hi, hb_lo);
      k_w2<1><<<640, 256, 0, stream>>>(hb_hi, hb_lo,
          w2 + (size_t)l * NEXP * 2048 * DM, counts, aoff, y);
      k_combine_norm<0><<<TOK, 256, 0, stream>>>(y, aoff, tok_e, tok_pos, tok_gate,
          x, attn_nw + (size_t)(l + 1) * DM, xn_hi, xn_lo, counts);
    } else {
      k_w13<0><<<1280, 256, 0, stream>>>(xn_hi, xn_lo,
          w1t_hi, w1t_lo, w3t_hi, w3t_lo,
          lists, counts, aoff, hb_hi, nullptr);
      k_w2<0><<<640, 256, 0, stream>>>(hb_hi, hb_lo,
          w2 + (size_t)l * NEXP * 2048 * DM, counts, aoff, y);
      k_combine_norm<1><<<TOK, 256, 0, stream>>>(y, aoff, tok_e, tok_pos, tok_gate,
          x, fin_nw, xnb, nullptr, nullptr);
    }
  }
  k_logits<<<2048, 512, 0, stream>>>(xnb, embB, out);
}

// Round 26
// 1317.988 us; speedup vs baseline: 1.0379x; 1.0379x over previous
//
#include <hip/hip_runtime.h>
#include <math.h>

typedef unsigned short u16;
typedef unsigned int u32;
typedef __attribute__((ext_vector_type(8))) short bf16x8;
typedef __attribute__((ext_vector_type(4))) float f32x4;

#define TOK 2048     // B*S
#define SEQ 1024
#define DM 1024
#define NEXP 8
#define VOCAB 32000
#define NL 2
#define SLOTS 5120   // max 64-aligned padded expert rows: 4096 + 8*63 < 5120
#define APAD 40      // padded u16 row for 32-k tiles (80B)

__device__ __forceinline__ float bf2f(u16 v) {
  u32 u = ((u32)v) << 16; float f; __builtin_memcpy(&f, &u, 4); return f;
}
__device__ __forceinline__ u16 f2bf(float f) {
  u32 u; __builtin_memcpy(&u, &f, 4);
  u += 0x7fffu + ((u >> 16) & 1u);   // RNE
  return (u16)(u >> 16);
}
__device__ __forceinline__ void split8(const float* v, u16* hi, u16* lo) {
#pragma unroll
  for (int j = 0; j < 8; j++) {
    hi[j] = f2bf(v[j]);
    lo[j] = f2bf(v[j] - bf2f(hi[j]));
  }
}

// ---------------- f32 -> bf16 convert (embed table)
__global__ __launch_bounds__(256) void k_f2bf(const float* __restrict__ in,
                                              u16* __restrict__ out, long n4) {
  long i = (long)blockIdx.x * 256 + threadIdx.x;
  long stride = (long)gridDim.x * 256;
  for (; i < n4; i += stride) {
    float4 v = ((const float4*)in)[i];
    ushort4 o;
    o.x = f2bf(v.x); o.y = f2bf(v.y); o.z = f2bf(v.z); o.w = f2bf(v.w);
    ((ushort4*)out)[i] = o;
  }
}

// ---------------- shared in-register rmsnorm tail
__device__ __forceinline__ void norm_emit_hl(float4 v, const float* __restrict__ w,
    u16* __restrict__ ohi, u16* __restrict__ olo, int t) {
  float ss = v.x * v.x + v.y * v.y + v.z * v.z + v.w * v.w;
  for (int off = 32; off; off >>= 1) ss += __shfl_xor(ss, off);
  __shared__ float red[4];
  if ((threadIdx.x & 63) == 0) red[threadIdx.x >> 6] = ss;
  __syncthreads();
  float tot = red[0] + red[1] + red[2] + red[3];
  float sc = rsqrtf(tot * (1.0f / 1024.0f) + 1e-6f);
  float4 wv = ((const float4*)w)[threadIdx.x];
  float o[4] = {v.x * sc * wv.x, v.y * sc * wv.y, v.z * sc * wv.z, v.w * sc * wv.w};
  ushort4 hi, lo;
  hi.x = f2bf(o[0]); lo.x = f2bf(o[0] - bf2f(hi.x));
  hi.y = f2bf(o[1]); lo.y = f2bf(o[1] - bf2f(hi.y));
  hi.z = f2bf(o[2]); lo.z = f2bf(o[2] - bf2f(hi.z));
  hi.w = f2bf(o[3]); lo.w = f2bf(o[3] - bf2f(hi.w));
  ((ushort4*)(ohi + (long)t * DM))[threadIdx.x] = hi;
  ((ushort4*)(olo + (long)t * DM))[threadIdx.x] = lo;
}
__device__ __forceinline__ void norm_emit_b(float4 v, const float* __restrict__ w,
    u16* __restrict__ out, int t) {
  float ss = v.x * v.x + v.y * v.y + v.z * v.z + v.w * v.w;
  for (int off = 32; off; off >>= 1) ss += __shfl_xor(ss, off);
  __shared__ float red[4];
  if ((threadIdx.x & 63) == 0) red[threadIdx.x >> 6] = ss;
  __syncthreads();
  float tot = red[0] + red[1] + red[2] + red[3];
  float sc = rsqrtf(tot * (1.0f / 1024.0f) + 1e-6f);
  float4 wv = ((const float4*)w)[threadIdx.x];
  ushort4 o;
  o.x = f2bf(v.x * sc * wv.x); o.y = f2bf(v.y * sc * wv.y);
  o.z = f2bf(v.z * sc * wv.z); o.w = f2bf(v.w * sc * wv.w);
  ((ushort4*)(out + (long)t * DM))[threadIdx.x] = o;
}

// ---------------- embedding gather fused with first rmsnorm (+zero counts)
__global__ __launch_bounds__(256) void k_gather_norm(const int* __restrict__ tok,
    const float* __restrict__ embed, const float* __restrict__ w,
    float* __restrict__ x, u16* __restrict__ ohi, u16* __restrict__ olo,
    int* __restrict__ counts) {
  int t = blockIdx.x;
  if (t == 0 && threadIdx.x < NEXP) counts[threadIdx.x] = 0;
  float4 v = ((const float4*)(embed + (long)tok[t] * DM))[threadIdx.x];
  ((float4*)(x + (long)t * DM))[threadIdx.x] = v;
  norm_emit_hl(v, w, ohi, olo, t);
}

// ---------------- MFMA flash attention: reads pre-split qkv hi/lo bf16
#define KP 72
#define VP 40
#define PP 36
__global__ __launch_bounds__(256) void k_attn(const u16* __restrict__ qhi,
    const u16* __restrict__ qlo, u16* __restrict__ chi, u16* __restrict__ clo) {
  __shared__ u16 Ksh[32 * KP], Ksl[32 * KP];
  __shared__ u16 Vsh[64 * VP], Vsl[64 * VP];
  __shared__ float Ps[4][16 * PP];
  int bid = blockIdx.x;
  int xcd = bid & 7, r = bid >> 3;
  int bh = xcd * 4 + (r >> 4);
  int qt = 15 - (r & 15);
  int b = bh >> 4, h = bh & 15;
  int tid = threadIdx.x, w = tid >> 6, lane = tid & 63;
  int lrow = lane & 15, lgrp = lane >> 4;
  int q0 = qt * 64;
  long qrow = (long)(b * SEQ + q0 + w * 16 + lrow);
  bf16x8 qh[2], ql[2];
#pragma unroll
  for (int dsl = 0; dsl < 2; dsl++) {
    long off = qrow * 3072 + h * 64 + dsl * 32 + lgrp * 8;
    qh[dsl] = *(const bf16x8*)(qhi + off);
    ql[dsl] = *(const bf16x8*)(qlo + off);
  }
  f32x4 cacc[4] = {};
  float mst[4], lst[4];
#pragma unroll
  for (int j = 0; j < 4; j++) { mst[j] = -__builtin_inff(); lst[j] = 0.0f; }
  int srow = tid >> 3, dchunk = (tid & 7) * 8;
  for (int s0 = 0; s0 < q0 + 64; s0 += 32) {
    long kvrow = (long)(b * SEQ + s0 + srow) * 3072 + h * 64;
    {
      *(uint4*)(Ksh + srow * KP + dchunk) = *(const uint4*)(qhi + kvrow + 1024 + dchunk);
      *(uint4*)(Ksl + srow * KP + dchunk) = *(const uint4*)(qlo + kvrow + 1024 + dchunk);
      uint4 hv4 = *(const uint4*)(qhi + kvrow + 2048 + dchunk);
      uint4 lv4 = *(const uint4*)(qlo + kvrow + 2048 + dchunk);
      const u16* hp = (const u16*)&hv4;
      const u16* lp = (const u16*)&lv4;
#pragma unroll
      for (int j = 0; j < 8; j++) {
        Vsh[(dchunk + j) * VP + srow] = hp[j];
        Vsl[(dchunk + j) * VP + srow] = lp[j];
      }
    }
    __syncthreads();
    f32x4 sacc[2] = {};
#pragma unroll
    for (int sf = 0; sf < 2; sf++)
#pragma unroll
      for (int dsl = 0; dsl < 2; dsl++) {
        bf16x8 kh = *(const bf16x8*)(Ksh + (sf * 16 + lrow) * KP + dsl * 32 + lgrp * 8);
        bf16x8 kl = *(const bf16x8*)(Ksl + (sf * 16 + lrow) * KP + dsl * 32 + lgrp * 8);
        sacc[sf] = __builtin_amdgcn_mfma_f32_16x16x32_bf16(qh[dsl], kh, sacc[sf], 0, 0, 0);
        sacc[sf] = __builtin_amdgcn_mfma_f32_16x16x32_bf16(qh[dsl], kl, sacc[sf], 0, 0, 0);
        sacc[sf] = __builtin_amdgcn_mfma_f32_16x16x32_bf16(ql[dsl], kh, sacc[sf], 0, 0, 0);
      }
#pragma unroll
    for (int sf = 0; sf < 2; sf++)
#pragma unroll
      for (int j = 0; j < 4; j++) {
        int col = s0 + sf * 16 + lrow;
        int row = q0 + w * 16 + lgrp * 4 + j;
        float v = sacc[sf][j] * 0.125f;
        sacc[sf][j] = (col <= row) ? v : -1e30f;
      }
    float fac[4];
#pragma unroll
    for (int j = 0; j < 4; j++) {
      float mx = fmaxf(sacc[0][j], sacc[1][j]);
      for (int off = 1; off < 16; off <<= 1) mx = fmaxf(mx, __shfl_xor(mx, off));
      float mnew = fmaxf(mst[j], mx);
      float f = __expf(mst[j] - mnew);
      mst[j] = mnew;
      float p0 = __expf(sacc[0][j] - mnew);
      float p1 = __expf(sacc[1][j] - mnew);
      sacc[0][j] = p0; sacc[1][j] = p1;
      float ps = p0 + p1;
      for (int off = 1; off < 16; off <<= 1) ps += __shfl_xor(ps, off);
      lst[j] = lst[j] * f + ps;
      fac[j] = f;
    }
#pragma unroll
    for (int n = 0; n < 4; n++)
#pragma unroll
      for (int j = 0; j < 4; j++) cacc[n][j] *= fac[j];
#pragma unroll
    for (int sf = 0; sf < 2; sf++)
#pragma unroll
      for (int j = 0; j < 4; j++)
        Ps[w][(lgrp * 4 + j) * PP + sf * 16 + lrow] = sacc[sf][j];
    float pv[8];
#pragma unroll
    for (int j = 0; j < 8; j++) pv[j] = Ps[w][lrow * PP + lgrp * 8 + j];
    u16 phi[8], plo[8];
    split8(pv, phi, plo);
    bf16x8 ph = *(bf16x8*)phi, pl = *(bf16x8*)plo;
#pragma unroll
    for (int n = 0; n < 4; n++) {
      bf16x8 vh = *(const bf16x8*)(Vsh + (n * 16 + lrow) * VP + lgrp * 8);
      bf16x8 vl = *(const bf16x8*)(Vsl + (n * 16 + lrow) * VP + lgrp * 8);
      cacc[n] = __builtin_amdgcn_mfma_f32_16x16x32_bf16(ph, vh, cacc[n], 0, 0, 0);
      cacc[n] = __builtin_amdgcn_mfma_f32_16x16x32_bf16(ph, vl, cacc[n], 0, 0, 0);
      cacc[n] = __builtin_amdgcn_mfma_f32_16x16x32_bf16(pl, vh, cacc[n], 0, 0, 0);
    }
    __syncthreads();
  }
#pragma unroll
  for (int n = 0; n < 4; n++)
#pragma unroll
    for (int j = 0; j < 4; j++) {
      long t = (long)(b * SEQ + q0 + w * 16 + lgrp * 4 + j);
      float v = cacc[n][j] / lst[j];
      u16 hv = f2bf(v);
      chi[t * DM + h * 64 + n * 16 + lrow] = hv;
      clo[t * DM + h * 64 + n * 16 + lrow] = f2bf(v - bf2f(hv));
    }
}

// ======== shared GEMM machinery ====

__device__ __forceinline__ void stageB_tr(const float* __restrict__ B, int ldb,
    int k0, int n0, u16* Bh, u16* Bl, int tid, int split) {
#pragma unroll
  for (int ph = 0; ph < 2; ph++) {
    int c = tid + 256 * ph;
    int nr = c & 127;
    int ks = c >> 7;
    const float* src = B + (long)(k0 + ks * 8) * ldb + n0 + nr;
    float v[8];
#pragma unroll
    for (int j = 0; j < 8; j++) v[j] = src[(long)j * ldb];
    u16 hi[8];
#pragma unroll
    for (int j = 0; j < 8; j++) hi[j] = f2bf(v[j]);
    *(uint4*)(Bh + nr * APAD + ks * 8) = *(uint4*)hi;
    if (split) {
      u16 lo[8];
#pragma unroll
      for (int j = 0; j < 8; j++) lo[j] = f2bf(v[j] - bf2f(hi[j]));
      *(uint4*)(Bl + nr * APAD + ks * 8) = *(uint4*)lo;
    }
  }
}

// ---------------- wo projection: 64x128 tile, grid 256 (full machine), split-3
__global__ __launch_bounds__(256) void k_wo(
    const u16* __restrict__ Ahi, const u16* __restrict__ Alo,
    const float* __restrict__ B, float* __restrict__ C) {
  __shared__ u16 Ah[64 * APAD], Al[64 * APAD], Bh[128 * APAD], Bl[128 * APAD];
  int bid = blockIdx.x;
  int n0 = (bid & 7) * 128;
  int m0 = (bid >> 3) * 64;
  int tid = threadIdx.x, lane = tid & 63, w = tid >> 6;
  int wr = w >> 1, wc = w & 1, lrow = lane & 15, lgrp = lane >> 4;
  f32x4 acc[2][4] = {};
  for (int k0 = 0; k0 < 1024; k0 += 32) {
    {
      int row = tid >> 2, kc = tid & 3;
      long off = (long)(m0 + row) * DM + k0 + kc * 8;
      *(uint4*)(Ah + row * APAD + kc * 8) = *(const uint4*)(Ahi + off);
      *(uint4*)(Al + row * APAD + kc * 8) = *(const uint4*)(Alo + off);
    }
    stageB_tr(B, 1024, k0, n0, Bh, Bl, tid, 1);
    __syncthreads();
    bf16x8 ah[2], al[2], bh[4], bl[4];
#pragma unroll
    for (int i = 0; i < 2; i++) {
      ah[i] = *(const bf16x8*)(Ah + (wr * 32 + i * 16 + lrow) * APAD + lgrp * 8);
      al[i] = *(const bf16x8*)(Al + (wr * 32 + i * 16 + lrow) * APAD + lgrp * 8);
    }
#pragma unroll
    for (int j = 0; j < 4; j++) {
      bh[j] = *(const bf16x8*)(Bh + (wc * 64 + j * 16 + lrow) * APAD + lgrp * 8);
      bl[j] = *(const bf16x8*)(Bl + (wc * 64 + j * 16 + lrow) * APAD + lgrp * 8);
    }
#pragma unroll
    for (int i = 0; i < 2; i++)
#pragma unroll
      for (int j = 0; j < 4; j++) {
        acc[i][j] = __builtin_amdgcn_mfma_f32_16x16x32_bf16(ah[i], bh[j], acc[i][j], 0, 0, 0);
        acc[i][j] = __builtin_amdgcn_mfma_f32_16x16x32_bf16(ah[i], bl[j], acc[i][j], 0, 0, 0);
        acc[i][j] = __builtin_amdgcn_mfma_f32_16x16x32_bf16(al[i], bh[j], acc[i][j], 0, 0, 0);
      }
    __syncthreads();
  }
#pragma unroll
  for (int i = 0; i < 2; i++)
#pragma unroll
    for (int j = 0; j < 4; j++) {
      int col = n0 + wc * 64 + j * 16 + lrow;
#pragma unroll
      for (int jj = 0; jj < 4; jj++) {
        int r = m0 + wr * 32 + i * 16 + lgrp * 4 + jj;
        C[(long)r * DM + col] += acc[i][j][jj];
      }
    }
}

// ---------------- fused QKV + RoPE: 64x128 tile, grid 768 (3 blocks/CU)
__global__ __launch_bounds__(256) void k_gemm_qkv(
    const u16* __restrict__ Ahi, const u16* __restrict__ Alo,
    const float* __restrict__ Bq, const float* __restrict__ Bk,
    const float* __restrict__ Bv, u16* __restrict__ Chi, u16* __restrict__ Clo) {
  __shared__ u16 Ah[64 * APAD], Al[64 * APAD], Bh[128 * APAD], Bl[128 * APAD];
  int bid = blockIdx.x;
  int xcd = bid & 7, r = bid >> 3;
  int nb = xcd * 3 + r / 32;
  int m0 = (r & 31) * 64;
  const float* B = (nb < 8) ? Bq : (nb < 16) ? Bk : Bv;
  int bn0 = (nb & 7) * 128;
  int tid = threadIdx.x, lane = tid & 63, w = tid >> 6;
  int wr = w >> 1, wc = w & 1, lrow = lane & 15, lgrp = lane >> 4;
  f32x4 acc[2][4] = {};
  for (int k0 = 0; k0 < 1024; k0 += 32) {
    {
      int row = tid >> 2, kc = tid & 3;
      long off = (long)(m0 + row) * DM + k0 + kc * 8;
      *(uint4*)(Ah + row * APAD + kc * 8) = *(const uint4*)(Ahi + off);
      *(uint4*)(Al + row * APAD + kc * 8) = *(const uint4*)(Alo + off);
    }
    stageB_tr(B, 1024, k0, bn0, Bh, Bl, tid, 1);
    __syncthreads();
    bf16x8 ah[2], al[2], bh[4], bl[4];
#pragma unroll
    for (int i = 0; i < 2; i++) {
      ah[i] = *(const bf16x8*)(Ah + (wr * 32 + i * 16 + lrow) * APAD + lgrp * 8);
      al[i] = *(const bf16x8*)(Al + (wr * 32 + i * 16 + lrow) * APAD + lgrp * 8);
    }
#pragma unroll
    for (int j = 0; j < 4; j++) {
      bh[j] = *(const bf16x8*)(Bh + (wc * 64 + j * 16 + lrow) * APAD + lgrp * 8);
      bl[j] = *(const bf16x8*)(Bl + (wc * 64 + j * 16 + lrow) * APAD + lgrp * 8);
    }
#pragma unroll
    for (int i = 0; i < 2; i++)
#pragma unroll
      for (int j = 0; j < 4; j++) {
        acc[i][j] = __builtin_amdgcn_mfma_f32_16x16x32_bf16(ah[i], bh[j], acc[i][j], 0, 0, 0);
        acc[i][j] = __builtin_amdgcn_mfma_f32_16x16x32_bf16(ah[i], bl[j], acc[i][j], 0, 0, 0);
        acc[i][j] = __builtin_amdgcn_mfma_f32_16x16x32_bf16(al[i], bh[j], acc[i][j], 0, 0, 0);
      }
    __syncthreads();
  }
  if (nb < 16) {
    float inv1 = exp2f((float)lrow * (-13.287712379549449f / 32.0f));
    float inv2 = exp2f((float)(lrow + 16) * (-13.287712379549449f / 32.0f));
#pragma unroll
    for (int i = 0; i < 2; i++)
#pragma unroll
      for (int jj = 0; jj < 4; jj++) {
        int rr = m0 + wr * 32 + i * 16 + lgrp * 4 + jj;
        float s = (float)(rr & (SEQ - 1));
        float sn1, cs1, sn2, cs2;
        sincosf(s * inv1, &sn1, &cs1);
        sincosf(s * inv2, &sn2, &cs2);
        float q1 = acc[i][0][jj], q2 = acc[i][2][jj];
        acc[i][0][jj] = q1 * cs1 - q2 * sn1;
        acc[i][2][jj] = q1 * sn1 + q2 * cs1;
        float p1 = acc[i][1][jj], p2 = acc[i][3][jj];
        acc[i][1][jj] = p1 * cs2 - p2 * sn2;
        acc[i][3][jj] = p1 * sn2 + p2 * cs2;
      }
  }
#pragma unroll
  for (int i = 0; i < 2; i++)
#pragma unroll
    for (int j = 0; j < 4; j++) {
      int col = nb * 128 + wc * 64 + j * 16 + lrow;
#pragma unroll
      for (int jj = 0; jj < 4; jj++) {
        int rr = m0 + wr * 32 + i * 16 + lgrp * 4 + jj;
        float v = acc[i][j][jj];
        u16 hv = f2bf(v);
        Chi[(long)rr * 3072 + col] = hv;
        Clo[(long)rr * 3072 + col] = f2bf(v - bf2f(hv));
      }
    }
}

// ---------------- fused MoE up-projection + silu: gate and up via TWO k-passes
// over one shared B buffer (30 KB LDS -> 5 blocks/CU); writes hb hi/lo directly
template <int SPLIT>
__global__ __launch_bounds__(256) void k_w13(
    const u16* __restrict__ Ahi, const u16* __restrict__ Alo,
    const float* __restrict__ W1, const float* __restrict__ W3,
    const int* __restrict__ lists, const int* __restrict__ counts,
    const int* __restrict__ aoff,
    u16* __restrict__ hhi, u16* __restrict__ hlo) {
  int bid = blockIdx.x;
  int xcd = bid & 7, r = bid >> 3;      // r 0..159
  int nb = xcd * 2 + r / 80;            // 2 n-panels per XCD (0..15)
  int m0 = (r % 80) * 64;               // m fastest (80 panels of 64)
  int e = -1;
#pragma unroll
  for (int i = 0; i < NEXP; i++)
    if (m0 >= aoff[i] && m0 < aoff[i + 1]) e = i;
  if (e < 0) return;
  int lr0 = m0 - aoff[e];
  int Mc = counts[e];
  if (lr0 >= Mc) return;
  const float* B1 = W1 + (size_t)e * 1024 * 2048;
  const float* B3 = W3 + (size_t)e * 1024 * 2048;
  int bn0 = nb * 128;
  const int* lst = lists + e * TOK;
  __shared__ u16 Ah[64 * APAD], Bh[128 * APAD];
  __shared__ u16 Al[SPLIT ? 64 * APAD : 1], Bl[SPLIT ? 128 * APAD : 1];
  int tid = threadIdx.x, lane = tid & 63, w = tid >> 6;
  int wr = w >> 1, wc = w & 1, lrow = lane & 15, lgrp = lane >> 4;
  f32x4 acc1[2][4] = {}, acc3[2][4] = {};
  auto kpass = [&](const float* B, f32x4 (&acc)[2][4]) {
    for (int k0 = 0; k0 < 1024; k0 += 32) {
      {  // A: 64 gathered rows, single pass
        int row = tid >> 2, kc = tid & 3;
        uint4 vh = make_uint4(0, 0, 0, 0), vl = make_uint4(0, 0, 0, 0);
        if (lr0 + row < Mc) {
          long off = (long)lst[lr0 + row] * DM + k0 + kc * 8;
          vh = *(const uint4*)(Ahi + off);
          if (SPLIT) vl = *(const uint4*)(Alo + off);
        }
        *(uint4*)(Ah + row * APAD + kc * 8) = vh;
        if (SPLIT) *(uint4*)(Al + row * APAD + kc * 8) = vl;
      }
      stageB_tr(B, 2048, k0, bn0, Bh, Bl, tid, SPLIT);
      __syncthreads();
      bf16x8 ah[2], bh[4];
#pragma unroll
      for (int i = 0; i < 2; i++)
        ah[i] = *(const bf16x8*)(Ah + (wr * 32 + i * 16 + lrow) * APAD + lgrp * 8);
#pragma unroll
      for (int j = 0; j < 4; j++)
        bh[j] = *(const bf16x8*)(Bh + (wc * 64 + j * 16 + lrow) * APAD + lgrp * 8);
#pragma unroll
      for (int i = 0; i < 2; i++)
#pragma unroll
        for (int j = 0; j < 4; j++)
          acc[i][j] = __builtin_amdgcn_mfma_f32_16x16x32_bf16(ah[i], bh[j], acc[i][j], 0, 0, 0);
      if (SPLIT) {
        bf16x8 al[2], bl[4];
#pragma unroll
        for (int i = 0; i < 2; i++)
          al[i] = *(const bf16x8*)(Al + (wr * 32 + i * 16 + lrow) * APAD + lgrp * 8);
#pragma unroll
        for (int j = 0; j < 4; j++)
          bl[j] = *(const bf16x8*)(Bl + (wc * 64 + j * 16 + lrow) * APAD + lgrp * 8);
#pragma unroll
        for (int i = 0; i < 2; i++)
#pragma unroll
          for (int j = 0; j < 4; j++) {
            acc[i][j] = __builtin_amdgcn_mfma_f32_16x16x32_bf16(ah[i], bl[j], acc[i][j], 0, 0, 0);
            acc[i][j] = __builtin_amdgcn_mfma_f32_16x16x32_bf16(al[i], bh[j], acc[i][j], 0, 0, 0);
          }
      }
      __syncthreads();
    }
  };
  kpass(B1, acc1);   // gate = A @ W1
  kpass(B3, acc3);   // up   = A @ W3
#pragma unroll
  for (int i = 0; i < 2; i++)
#pragma unroll
    for (int j = 0; j < 4; j++) {
      int col = bn0 + wc * 64 + j * 16 + lrow;
#pragma unroll
      for (int jj = 0; jj < 4; jj++) {
        int rl = wr * 32 + i * 16 + lgrp * 4 + jj;
        if (lr0 + rl >= Mc) continue;
        float g = acc1[i][j][jj], u = acc3[i][j][jj];
        float o = g / (1.0f + __expf(-g)) * u;
        u16 hv = f2bf(o);
        hhi[(long)(m0 + rl) * 2048 + col] = hv;
        if (SPLIT) hlo[(long)(m0 + rl) * 2048 + col] = f2bf(o - bf2f(hv));
      }
    }
}

// ---------------- batched MoE down-projection: 64x128 tile, grid 640 (2.5/CU)
template <int SPLIT>
__global__ __launch_bounds__(256) void k_w2(
    const u16* __restrict__ Ahi, const u16* __restrict__ Alo,
    const float* __restrict__ W2,
    const int* __restrict__ counts, const int* __restrict__ aoff,
    float* __restrict__ y) {
  int bid = blockIdx.x;
  int n0 = (bid & 7) * 128;
  int m0 = (bid >> 3) * 64;
  int e = -1;
#pragma unroll
  for (int i = 0; i < NEXP; i++)
    if (m0 >= aoff[i] && m0 < aoff[i + 1]) e = i;
  if (e < 0) return;
  int lr0 = m0 - aoff[e];
  int Mc = counts[e];
  if (lr0 >= Mc) return;
  const float* B = W2 + (size_t)e * 2048 * 1024;
  __shared__ u16 Ah[64 * APAD], Bh[128 * APAD];
  __shared__ u16 Al[SPLIT ? 64 * APAD : 1], Bl[SPLIT ? 128 * APAD : 1];
  int tid = threadIdx.x, lane = tid & 63, w = tid >> 6;
  int wr = w >> 1, wc = w & 1, lrow = lane & 15, lgrp = lane >> 4;
  f32x4 acc[2][4] = {};
  for (int k0 = 0; k0 < 2048; k0 += 32) {
    {
      int row = tid >> 2, kc = tid & 3;
      long off = (long)(m0 + row) * 2048 + k0 + kc * 8;
      *(uint4*)(Ah + row * APAD + kc * 8) = *(const uint4*)(Ahi + off);
      if (SPLIT) *(uint4*)(Al + row * APAD + kc * 8) = *(const uint4*)(Alo + off);
    }
    stageB_tr(B, 1024, k0, n0, Bh, Bl, tid, SPLIT);
    __syncthreads();
    bf16x8 ah[2], bh[4];
#pragma unroll
    for (int i = 0; i < 2; i++)
      ah[i] = *(const bf16x8*)(Ah + (wr * 32 + i * 16 + lrow) * APAD + lgrp * 8);
#pragma unroll
    for (int j = 0; j < 4; j++)
      bh[j] = *(const bf16x8*)(Bh + (wc * 64 + j * 16 + lrow) * APAD + lgrp * 8);
#pragma unroll
    for (int i = 0; i < 2; i++)
#pragma unroll
      for (int j = 0; j < 4; j++)
        acc[i][j] = __builtin_amdgcn_mfma_f32_16x16x32_bf16(ah[i], bh[j], acc[i][j], 0, 0, 0);
    if (SPLIT) {
      bf16x8 al[2], bl[4];
#pragma unroll
      for (int i = 0; i < 2; i++)
        al[i] = *(const bf16x8*)(Al + (wr * 32 + i * 16 + lrow) * APAD + lgrp * 8);
#pragma unroll
      for (int j = 0; j < 4; j++)
        bl[j] = *(const bf16x8*)(Bl + (wc * 64 + j * 16 + lrow) * APAD + lgrp * 8);
#pragma unroll
      for (int i = 0; i < 2; i++)
#pragma unroll
        for (int j = 0; j < 4; j++) {
          acc[i][j] = __builtin_amdgcn_mfma_f32_16x16x32_bf16(ah[i], bl[j], acc[i][j], 0, 0, 0);
          acc[i][j] = __builtin_amdgcn_mfma_f32_16x16x32_bf16(al[i], bh[j], acc[i][j], 0, 0, 0);
        }
    }
    __syncthreads();
  }
#pragma unroll
  for (int i = 0; i < 2; i++)
#pragma unroll
    for (int j = 0; j < 4; j++) {
      int col = n0 + wc * 64 + j * 16 + lrow;
#pragma unroll
      for (int jj = 0; jj < 4; jj++) {
        int rl = wr * 32 + i * 16 + lgrp * 4 + jj;
        if (lr0 + rl >= Mc) continue;
        y[(long)(m0 + rl) * DM + col] = acc[i][j][jj];
      }
    }
}

// ---------------- combine + next-layer norm fused (+zero counts when !FINAL)
template <int FINAL>
__global__ __launch_bounds__(256) void k_combine_norm(const float* __restrict__ y,
    const int* __restrict__ aoff, const int* __restrict__ tok_e,
    const int* __restrict__ tok_pos, const float* __restrict__ tok_gate,
    float* __restrict__ x, const float* __restrict__ wnext,
    u16* __restrict__ ohi, u16* __restrict__ olo, int* __restrict__ counts) {
  int t = blockIdx.x;
  if (!FINAL && t == 0 && threadIdx.x < NEXP) counts[threadIdx.x] = 0;
  float4 acc = ((float4*)(x + (long)t * DM))[threadIdx.x];
#pragma unroll
  for (int j = 0; j < 2; j++) {
    int e = tok_e[t * 2 + j];
    long g = aoff[e] + tok_pos[t * 2 + j];
    float gt = tok_gate[t * 2 + j];
    float4 yv = ((const float4*)(y + g * DM))[threadIdx.x];
    acc.x += gt * yv.x; acc.y += gt * yv.y;
    acc.z += gt * yv.z; acc.w += gt * yv.w;
  }
  ((float4*)(x + (long)t * DM))[threadIdx.x] = acc;
  if (FINAL) norm_emit_b(acc, wnext, ohi, t);
  else norm_emit_hl(acc, wnext, ohi, olo, t);
}

// ---------------- logits fragment compute
__device__ __forceinline__ void logits_mma(const u16* As, const u16* Bs,
    f32x4 (&acc)[4][4], int wr, int wc, int lrow, int lgrp) {
  bf16x8 af[4], bfr[4];
#pragma unroll
  for (int i = 0; i < 4; i++) {
    af[i] = *(const bf16x8*)(As + (wr * 64 + i * 16 + lrow) * APAD + lgrp * 8);
    bfr[i] = *(const bf16x8*)(Bs + (wc * 64 + i * 16 + lrow) * APAD + lgrp * 8);
  }
#pragma unroll
  for (int i = 0; i < 4; i++)
#pragma unroll
    for (int j = 0; j < 4; j++)
      acc[i][j] = __builtin_amdgcn_mfma_f32_16x16x32_bf16(af[i], bfr[j], acc[i][j], 0, 0, 0);
}

// ---------------- logits GEMM (r14 structure, measured 188-194 us)
__global__ __launch_bounds__(512) void k_logits(
    const u16* __restrict__ A, const u16* __restrict__ Bt,
    float* __restrict__ C) {
  __shared__ u16 AsA[256 * APAD], BsA[128 * APAD];
  __shared__ u16 AsB[256 * APAD], BsB[128 * APAD];
  int bid = blockIdx.x;
  int xcd = bid & 7, rank = bid >> 3;
  int bx = xcd * 32 + (rank >> 3);
  int by = rank & 7;
  if (bx >= VOCAB / 128) return;
  int m0 = by * 256, n0 = bx * 128;
  int tid = threadIdx.x, lane = tid & 63, w = tid >> 6;
  int wr = w >> 1, wc = w & 1;
  int lrow = lane & 15, lgrp = lane >> 4;
  int arow = tid >> 2, akc = tid & 3;
  f32x4 acc[4][4] = {};
  const u16* Ap = A + (long)(m0 + arow) * 1024 + akc * 8;
  const u16* Ap2 = A + (long)(m0 + arow + 128) * 1024 + akc * 8;
  const u16* Bp = Bt + (long)(n0 + arow) * 1024 + akc * 8;
  uint4 a0 = *(const uint4*)(Ap);
  uint4 a1 = *(const uint4*)(Ap2);
  uint4 b0 = *(const uint4*)(Bp);
  *(uint4*)(AsA + arow * APAD + akc * 8) = a0;
  *(uint4*)(AsA + (arow + 128) * APAD + akc * 8) = a1;
  *(uint4*)(BsA + arow * APAD + akc * 8) = b0;
  __syncthreads();
  for (int kt = 0; kt < 32; kt += 2) {
    {
      int k0 = (kt + 1) * 32;
      a0 = *(const uint4*)(Ap + k0);
      a1 = *(const uint4*)(Ap2 + k0);
      b0 = *(const uint4*)(Bp + k0);
    }
    logits_mma(AsA, BsA, acc, wr, wc, lrow, lgrp);
    *(uint4*)(AsB + arow * APAD + akc * 8) = a0;
    *(uint4*)(AsB + (arow + 128) * APAD + akc * 8) = a1;
    *(uint4*)(BsB + arow * APAD + akc * 8) = b0;
    __syncthreads();
    if (kt + 2 < 32) {
      int k0 = (kt + 2) * 32;
      a0 = *(const uint4*)(Ap + k0);
      a1 = *(const uint4*)(Ap2 + k0);
      b0 = *(const uint4*)(Bp + k0);
    }
    logits_mma(AsB, BsB, acc, wr, wc, lrow, lgrp);
    if (kt + 2 < 32) {
      *(uint4*)(AsA + arow * APAD + akc * 8) = a0;
      *(uint4*)(AsA + (arow + 128) * APAD + akc * 8) = a1;
      *(uint4*)(BsA + arow * APAD + akc * 8) = b0;
    }
    __syncthreads();
  }
#pragma unroll
  for (int i = 0; i < 4; i++)
#pragma unroll
    for (int j = 0; j < 4; j++) {
      int col = n0 + wc * 64 + j * 16 + lrow;
#pragma unroll
      for (int jj = 0; jj < 4; jj++) {
        int r = m0 + wr * 64 + i * 16 + lgrp * 4 + jj;
        C[(long)r * VOCAB + col] = acc[i][j][jj];
      }
    }
}

// ---------------- router fused with moe rmsnorm: top-2 + emit xn hi/lo
__global__ __launch_bounds__(256) void k_router_norm(const float* __restrict__ x,
    const float* __restrict__ nw, const float* __restrict__ rw,
    int* __restrict__ counts, int* __restrict__ lists,
    int* __restrict__ tok_e, int* __restrict__ tok_pos,
    float* __restrict__ tok_gate,
    u16* __restrict__ ohi, u16* __restrict__ olo) {
  int t = blockIdx.x * 4 + (threadIdx.x >> 6);
  int lane = threadIdx.x & 63;
  const float* xr = x + (long)t * DM;
  float xv[16], wv[16];
  float ss = 0.0f;
  float p[8] = {0, 0, 0, 0, 0, 0, 0, 0};
#pragma unroll
  for (int i = 0; i < 16; i++) {
    int d = lane + 64 * i;
    xv[i] = xr[d];
    wv[i] = nw[d];
    ss += xv[i] * xv[i];
    float xw = xv[i] * wv[i];
#pragma unroll
    for (int e = 0; e < 8; e++) p[e] += xw * rw[e * DM + d];
  }
  for (int off = 32; off; off >>= 1) ss += __shfl_xor(ss, off);
#pragma unroll
  for (int e = 0; e < 8; e++)
    for (int off = 32; off; off >>= 1) p[e] += __shfl_xor(p[e], off);
  float sc = rsqrtf(ss * (1.0f / 1024.0f) + 1e-6f);
#pragma unroll
  for (int i = 0; i < 16; i++) {
    int d = lane + 64 * i;
    float o = xv[i] * sc * wv[i];
    u16 h = f2bf(o);
    ohi[(long)t * DM + d] = h;
    olo[(long)t * DM + d] = f2bf(o - bf2f(h));
  }
  if (lane == 0) {
    int e0 = 0, e1 = -1;
    float v0 = -__builtin_inff(), v1 = -__builtin_inff();
    for (int e = 0; e < 8; e++) {
      float pe = p[e] * sc;
      if (pe > v0) { v1 = v0; e1 = e0; v0 = pe; e0 = e; }
      else if (pe > v1) { v1 = pe; e1 = e; }
    }
    float w0 = 1.0f / (1.0f + expf(v1 - v0));
    int pos0 = atomicAdd(&counts[e0], 1);
    lists[e0 * TOK + pos0] = t;
    tok_e[t * 2] = e0; tok_pos[t * 2] = pos0; tok_gate[t * 2] = w0;
    int pos1 = atomicAdd(&counts[e1], 1);
    lists[e1 * TOK + pos1] = t;
    tok_e[t * 2 + 1] = e1; tok_pos[t * 2 + 1] = pos1; tok_gate[t * 2 + 1] = 1.0f - w0;
  }
}

// ---------------- 64-aligned exclusive prefix of counts
__global__ void k_offsets(const int* __restrict__ counts, int* __restrict__ aoff) {
  if (threadIdx.x == 0 && blockIdx.x == 0) {
    int a = 0;
    for (int e = 0; e < NEXP; e++) {
      aoff[e] = a;
      a += (counts[e] + 63) & ~63;
    }
    aoff[NEXP] = a;
  }
}

extern "C" void kernel_launch(void* const* d_in, const int* in_sizes, int n_in,
                              void* d_out, int out_size, void* d_ws, size_t ws_size,
                              hipStream_t stream) {
  (void)in_sizes; (void)n_in; (void)out_size; (void)ws_size;
  const int* tokens = (const int*)d_in[0];
  const float* embed = (const float*)d_in[1];
  const float* attn_nw = (const float*)d_in[2];
  const float* wq = (const float*)d_in[3];
  const float* wk = (const float*)d_in[4];
  const float* wv = (const float*)d_in[5];
  const float* wo = (const float*)d_in[6];
  const float* moe_nw = (const float*)d_in[7];
  const float* rw = (const float*)d_in[8];
  const float* w1 = (const float*)d_in[9];
  const float* w2 = (const float*)d_in[10];
  const float* w3 = (const float*)d_in[11];
  const float* fin_nw = (const float*)d_in[12];
  float* out = (float*)d_out;

  // ---- scratch carved from d_out (262 MB; all dead before final logits GEMM)
  char* ob = (char*)d_out;
  auto carve = [&](size_t bytes) { char* r = ob; ob += (bytes + 255) & ~(size_t)255; return r; };
  u16*   qkv_hi = (u16*)carve((size_t)TOK * 3072 * 2);
  u16*   qkv_lo = (u16*)carve((size_t)TOK * 3072 * 2);
  u16*   ctx_hi = (u16*)carve((size_t)TOK * DM * 2);
  u16*   ctx_lo = (u16*)carve((size_t)TOK * DM * 2);
  float* x      = (float*)carve((size_t)TOK * DM * 4);
  u16*   hb_hi  = (u16*)carve((size_t)SLOTS * 2048 * 2);
  u16*   hb_lo  = (u16*)carve((size_t)SLOTS * 2048 * 2);
  float* y      = (float*)carve((size_t)SLOTS * 1024 * 4);
  int*   counts  = (int*)carve(NEXP * 4);
  int*   aoff    = (int*)carve((NEXP + 1) * 4);
  int*   lists   = (int*)carve((size_t)NEXP * TOK * 4);
  int*   tok_e   = (int*)carve((size_t)TOK * 2 * 4);
  int*   tok_pos = (int*)carve((size_t)TOK * 2 * 4);
  float* tok_gate= (float*)carve((size_t)TOK * 2 * 4);
  // ---- d_ws: buffers the final GEMM reads while d_out is being written
  char* wp = (char*)d_ws;
  auto wcarve = [&](size_t bytes) { char* r = wp; wp += (bytes + 255) & ~(size_t)255; return r; };
  u16* xn_hi = (u16*)wcarve((size_t)TOK * DM * 2);
  u16* xn_lo = (u16*)wcarve((size_t)TOK * DM * 2);
  u16* xnb   = (u16*)wcarve((size_t)TOK * DM * 2);
  u16* embB  = (u16*)wcarve((size_t)VOCAB * DM * 2);

  k_f2bf<<<4096, 256, 0, stream>>>(embed, embB, (long)VOCAB * DM / 4);
  k_gather_norm<<<TOK, 256, 0, stream>>>(tokens, embed, attn_nw, x, xn_hi, xn_lo, counts);

  for (int l = 0; l < NL; l++) {
    k_gemm_qkv<<<768, 256, 0, stream>>>(xn_hi, xn_lo,
        wq + (size_t)l * DM * DM, wk + (size_t)l * DM * DM, wv + (size_t)l * DM * DM,
        qkv_hi, qkv_lo);
    k_attn<<<512, 256, 0, stream>>>(qkv_hi, qkv_lo, ctx_hi, ctx_lo);
    k_wo<<<256, 256, 0, stream>>>(ctx_hi, ctx_lo, wo + (size_t)l * DM * DM, x);

    k_router_norm<<<TOK / 4, 256, 0, stream>>>(x, moe_nw + (size_t)l * DM,
        rw + (size_t)l * NEXP * DM, counts, lists, tok_e, tok_pos, tok_gate,
        xn_hi, xn_lo);
    k_offsets<<<1, 64, 0, stream>>>(counts, aoff);
    if (l < NL - 1) {
      k_w13<1><<<1280, 256, 0, stream>>>(xn_hi, xn_lo,
          w1 + (size_t)l * NEXP * DM * 2048, w3 + (size_t)l * NEXP * DM * 2048,
          lists, counts, aoff, hb_hi, hb_lo);
      k_w2<1><<<640, 256, 0, stream>>>(hb_hi, hb_lo,
          w2 + (size_t)l * NEXP * 2048 * DM, counts, aoff, y);
      k_combine_norm<0><<<TOK, 256, 0, stream>>>(y, aoff, tok_e, tok_pos, tok_gate,
          x, attn_nw + (size_t)(l + 1) * DM, xn_hi, xn_lo, counts);
    } else {
      k_w13<0><<<1280, 256, 0, stream>>>(xn_hi, xn_lo,
          w1 + (size_t)l * NEXP * DM * 2048, w3 + (size_t)l * NEXP * DM * 2048,
          lists, counts, aoff, hb_hi, nullptr);
      k_w2<0><<<640, 256, 0, stream>>>(hb_hi, hb_lo,
          w2 + (size_t)l * NEXP * 2048 * DM, counts, aoff, y);
      k_combine_norm<1><<<TOK, 256, 0, stream>>>(y, aoff, tok_e, tok_pos, tok_gate,
          x, fin_nw, xnb, nullptr, nullptr);
    }
  }
  k_logits<<<2048, 512, 0, stream>>>(xnb, embB, out);
}

// Round 27
// 1200.470 us; speedup vs baseline: 1.1395x; 1.0979x over previous
//
#include <hip/hip_runtime.h>
#include <math.h>

typedef unsigned short u16;
typedef unsigned int u32;
typedef __attribute__((ext_vector_type(8))) short bf16x8;
typedef __attribute__((ext_vector_type(4))) float f32x4;

#define TOK 2048     // B*S
#define SEQ 1024
#define DM 1024
#define NEXP 8
#define VOCAB 32000
#define NL 2
#define SLOTS 5120   // max 64-aligned padded expert rows: 4096 + 8*63 < 5120
#define APAD 40      // padded u16 row for 32-k tiles (80B)

__device__ __forceinline__ float bf2f(u16 v) {
  u32 u = ((u32)v) << 16; float f; __builtin_memcpy(&f, &u, 4); return f;
}
__device__ __forceinline__ u16 f2bf(float f) {
  u32 u; __builtin_memcpy(&u, &f, 4);
  u += 0x7fffu + ((u >> 16) & 1u);   // RNE
  return (u16)(u >> 16);
}
// HW packed f32->bf16 (RNE), gfx950: dst = bf16(a) | bf16(b)<<16
__device__ __forceinline__ u32 cvtpk_bf16(float a, float b) {
  u32 r; asm("v_cvt_pk_bf16_f32 %0, %1, %2" : "=v"(r) : "v"(a), "v"(b)); return r;
}
__device__ __forceinline__ void split8(const float* v, u16* hi, u16* lo) {
#pragma unroll
  for (int j = 0; j < 8; j++) {
    hi[j] = f2bf(v[j]);
    lo[j] = f2bf(v[j] - bf2f(hi[j]));
  }
}

// ---------------- f32 -> bf16 convert (embed table)
__global__ __launch_bounds__(256) void k_f2bf(const float* __restrict__ in,
                                              u16* __restrict__ out, long n4) {
  long i = (long)blockIdx.x * 256 + threadIdx.x;
  long stride = (long)gridDim.x * 256;
  for (; i < n4; i += stride) {
    float4 v = ((const float4*)in)[i];
    ushort4 o;
    o.x = f2bf(v.x); o.y = f2bf(v.y); o.z = f2bf(v.z); o.w = f2bf(v.w);
    ((ushort4*)out)[i] = o;
  }
}

// ---------------- shared in-register rmsnorm tail
__device__ __forceinline__ void norm_emit_hl(float4 v, const float* __restrict__ w,
    u16* __restrict__ ohi, u16* __restrict__ olo, int t) {
  float ss = v.x * v.x + v.y * v.y + v.z * v.z + v.w * v.w;
  for (int off = 32; off; off >>= 1) ss += __shfl_xor(ss, off);
  __shared__ float red[4];
  if ((threadIdx.x & 63) == 0) red[threadIdx.x >> 6] = ss;
  __syncthreads();
  float tot = red[0] + red[1] + red[2] + red[3];
  float sc = rsqrtf(tot * (1.0f / 1024.0f) + 1e-6f);
  float4 wv = ((const float4*)w)[threadIdx.x];
  float o[4] = {v.x * sc * wv.x, v.y * sc * wv.y, v.z * sc * wv.z, v.w * sc * wv.w};
  ushort4 hi, lo;
  hi.x = f2bf(o[0]); lo.x = f2bf(o[0] - bf2f(hi.x));
  hi.y = f2bf(o[1]); lo.y = f2bf(o[1] - bf2f(hi.y));
  hi.z = f2bf(o[2]); lo.z = f2bf(o[2] - bf2f(hi.z));
  hi.w = f2bf(o[3]); lo.w = f2bf(o[3] - bf2f(hi.w));
  ((ushort4*)(ohi + (long)t * DM))[threadIdx.x] = hi;
  ((ushort4*)(olo + (long)t * DM))[threadIdx.x] = lo;
}
__device__ __forceinline__ void norm_emit_b(float4 v, const float* __restrict__ w,
    u16* __restrict__ out, int t) {
  float ss = v.x * v.x + v.y * v.y + v.z * v.z + v.w * v.w;
  for (int off = 32; off; off >>= 1) ss += __shfl_xor(ss, off);
  __shared__ float red[4];
  if ((threadIdx.x & 63) == 0) red[threadIdx.x >> 6] = ss;
  __syncthreads();
  float tot = red[0] + red[1] + red[2] + red[3];
  float sc = rsqrtf(tot * (1.0f / 1024.0f) + 1e-6f);
  float4 wv = ((const float4*)w)[threadIdx.x];
  ushort4 o;
  o.x = f2bf(v.x * sc * wv.x); o.y = f2bf(v.y * sc * wv.y);
  o.z = f2bf(v.z * sc * wv.z); o.w = f2bf(v.w * sc * wv.w);
  ((ushort4*)(out + (long)t * DM))[threadIdx.x] = o;
}

// ---------------- embedding gather fused with first rmsnorm (+zero counts)
__global__ __launch_bounds__(256) void k_gather_norm(const int* __restrict__ tok,
    const float* __restrict__ embed, const float* __restrict__ w,
    float* __restrict__ x, u16* __restrict__ ohi, u16* __restrict__ olo,
    int* __restrict__ counts) {
  int t = blockIdx.x;
  if (t == 0 && threadIdx.x < NEXP) counts[threadIdx.x] = 0;
  float4 v = ((const float4*)(embed + (long)tok[t] * DM))[threadIdx.x];
  ((float4*)(x + (long)t * DM))[threadIdx.x] = v;
  norm_emit_hl(v, w, ohi, olo, t);
}

// ---------------- MFMA flash attention: reads pre-split qkv hi/lo bf16
#define KP 72
#define VP 40
#define PP 36
__global__ __launch_bounds__(256) void k_attn(const u16* __restrict__ qhi,
    const u16* __restrict__ qlo, u16* __restrict__ chi, u16* __restrict__ clo) {
  __shared__ u16 Ksh[32 * KP], Ksl[32 * KP];
  __shared__ u16 Vsh[64 * VP], Vsl[64 * VP];
  __shared__ float Ps[4][16 * PP];
  int bid = blockIdx.x;
  int xcd = bid & 7, r = bid >> 3;
  int bh = xcd * 4 + (r >> 4);
  int qt = 15 - (r & 15);
  int b = bh >> 4, h = bh & 15;
  int tid = threadIdx.x, w = tid >> 6, lane = tid & 63;
  int lrow = lane & 15, lgrp = lane >> 4;
  int q0 = qt * 64;
  long qrow = (long)(b * SEQ + q0 + w * 16 + lrow);
  bf16x8 qh[2], ql[2];
#pragma unroll
  for (int dsl = 0; dsl < 2; dsl++) {
    long off = qrow * 3072 + h * 64 + dsl * 32 + lgrp * 8;
    qh[dsl] = *(const bf16x8*)(qhi + off);
    ql[dsl] = *(const bf16x8*)(qlo + off);
  }
  f32x4 cacc[4] = {};
  float mst[4], lst[4];
#pragma unroll
  for (int j = 0; j < 4; j++) { mst[j] = -__builtin_inff(); lst[j] = 0.0f; }
  int srow = tid >> 3, dchunk = (tid & 7) * 8;
  for (int s0 = 0; s0 < q0 + 64; s0 += 32) {
    long kvrow = (long)(b * SEQ + s0 + srow) * 3072 + h * 64;
    {
      *(uint4*)(Ksh + srow * KP + dchunk) = *(const uint4*)(qhi + kvrow + 1024 + dchunk);
      *(uint4*)(Ksl + srow * KP + dchunk) = *(const uint4*)(qlo + kvrow + 1024 + dchunk);
      uint4 hv4 = *(const uint4*)(qhi + kvrow + 2048 + dchunk);
      uint4 lv4 = *(const uint4*)(qlo + kvrow + 2048 + dchunk);
      const u16* hp = (const u16*)&hv4;
      const u16* lp = (const u16*)&lv4;
#pragma unroll
      for (int j = 0; j < 8; j++) {
        Vsh[(dchunk + j) * VP + srow] = hp[j];
        Vsl[(dchunk + j) * VP + srow] = lp[j];
      }
    }
    __syncthreads();
    f32x4 sacc[2] = {};
#pragma unroll
    for (int sf = 0; sf < 2; sf++)
#pragma unroll
      for (int dsl = 0; dsl < 2; dsl++) {
        bf16x8 kh = *(const bf16x8*)(Ksh + (sf * 16 + lrow) * KP + dsl * 32 + lgrp * 8);
        bf16x8 kl = *(const bf16x8*)(Ksl + (sf * 16 + lrow) * KP + dsl * 32 + lgrp * 8);
        sacc[sf] = __builtin_amdgcn_mfma_f32_16x16x32_bf16(qh[dsl], kh, sacc[sf], 0, 0, 0);
        sacc[sf] = __builtin_amdgcn_mfma_f32_16x16x32_bf16(qh[dsl], kl, sacc[sf], 0, 0, 0);
        sacc[sf] = __builtin_amdgcn_mfma_f32_16x16x32_bf16(ql[dsl], kh, sacc[sf], 0, 0, 0);
      }
#pragma unroll
    for (int sf = 0; sf < 2; sf++)
#pragma unroll
      for (int j = 0; j < 4; j++) {
        int col = s0 + sf * 16 + lrow;
        int row = q0 + w * 16 + lgrp * 4 + j;
        float v = sacc[sf][j] * 0.125f;
        sacc[sf][j] = (col <= row) ? v : -1e30f;
      }
    float fac[4];
#pragma unroll
    for (int j = 0; j < 4; j++) {
      float mx = fmaxf(sacc[0][j], sacc[1][j]);
      for (int off = 1; off < 16; off <<= 1) mx = fmaxf(mx, __shfl_xor(mx, off));
      float mnew = fmaxf(mst[j], mx);
      float f = __expf(mst[j] - mnew);
      mst[j] = mnew;
      float p0 = __expf(sacc[0][j] - mnew);
      float p1 = __expf(sacc[1][j] - mnew);
      sacc[0][j] = p0; sacc[1][j] = p1;
      float ps = p0 + p1;
      for (int off = 1; off < 16; off <<= 1) ps += __shfl_xor(ps, off);
      lst[j] = lst[j] * f + ps;
      fac[j] = f;
    }
#pragma unroll
    for (int n = 0; n < 4; n++)
#pragma unroll
      for (int j = 0; j < 4; j++) cacc[n][j] *= fac[j];
#pragma unroll
    for (int sf = 0; sf < 2; sf++)
#pragma unroll
      for (int j = 0; j < 4; j++)
        Ps[w][(lgrp * 4 + j) * PP + sf * 16 + lrow] = sacc[sf][j];
    float pv[8];
#pragma unroll
    for (int j = 0; j < 8; j++) pv[j] = Ps[w][lrow * PP + lgrp * 8 + j];
    u16 phi[8], plo[8];
    split8(pv, phi, plo);
    bf16x8 ph = *(bf16x8*)phi, pl = *(bf16x8*)plo;
#pragma unroll
    for (int n = 0; n < 4; n++) {
      bf16x8 vh = *(const bf16x8*)(Vsh + (n * 16 + lrow) * VP + lgrp * 8);
      bf16x8 vl = *(const bf16x8*)(Vsl + (n * 16 + lrow) * VP + lgrp * 8);
      cacc[n] = __builtin_amdgcn_mfma_f32_16x16x32_bf16(ph, vh, cacc[n], 0, 0, 0);
      cacc[n] = __builtin_amdgcn_mfma_f32_16x16x32_bf16(ph, vl, cacc[n], 0, 0, 0);
      cacc[n] = __builtin_amdgcn_mfma_f32_16x16x32_bf16(pl, vh, cacc[n], 0, 0, 0);
    }
    __syncthreads();
  }
#pragma unroll
  for (int n = 0; n < 4; n++)
#pragma unroll
    for (int j = 0; j < 4; j++) {
      long t = (long)(b * SEQ + q0 + w * 16 + lgrp * 4 + j);
      float v = cacc[n][j] / lst[j];
      u16 hv = f2bf(v);
      chi[t * DM + h * 64 + n * 16 + lrow] = hv;
      clo[t * DM + h * 64 + n * 16 + lrow] = f2bf(v - bf2f(hv));
    }
}

// ======== shared GEMM machinery ====

__device__ __forceinline__ void stageB_tr(const float* __restrict__ B, int ldb,
    int k0, int n0, u16* Bh, u16* Bl, int tid, int split) {
#pragma unroll
  for (int ph = 0; ph < 2; ph++) {
    int c = tid + 256 * ph;
    int nr = c & 127;
    int ks = c >> 7;
    const float* src = B + (long)(k0 + ks * 8) * ldb + n0 + nr;
    float v[8];
#pragma unroll
    for (int j = 0; j < 8; j++) v[j] = src[(long)j * ldb];
    u32 h4[4];
#pragma unroll
    for (int j = 0; j < 4; j++) h4[j] = cvtpk_bf16(v[2 * j], v[2 * j + 1]);
    *(uint4*)(Bh + nr * APAD + ks * 8) = *(uint4*)h4;
    if (split) {
      u32 l4[4];
#pragma unroll
      for (int j = 0; j < 4; j++) {
        u32 b0 = h4[j] << 16, b1 = h4[j] & 0xffff0000u;
        float h0, h1;
        __builtin_memcpy(&h0, &b0, 4);
        __builtin_memcpy(&h1, &b1, 4);
        l4[j] = cvtpk_bf16(v[2 * j] - h0, v[2 * j + 1] - h1);
      }
      *(uint4*)(Bl + nr * APAD + ks * 8) = *(uint4*)l4;
    }
  }
}

// ---------------- wo projection: 64x128 tile, grid 256 (full machine), split-3
__global__ __launch_bounds__(256) void k_wo(
    const u16* __restrict__ Ahi, const u16* __restrict__ Alo,
    const float* __restrict__ B, float* __restrict__ C) {
  __shared__ u16 Ah[64 * APAD], Al[64 * APAD], Bh[128 * APAD], Bl[128 * APAD];
  int bid = blockIdx.x;
  int n0 = (bid & 7) * 128;
  int m0 = (bid >> 3) * 64;
  int tid = threadIdx.x, lane = tid & 63, w = tid >> 6;
  int wr = w >> 1, wc = w & 1, lrow = lane & 15, lgrp = lane >> 4;
  f32x4 acc[2][4] = {};
  for (int k0 = 0; k0 < 1024; k0 += 32) {
    {
      int row = tid >> 2, kc = tid & 3;
      long off = (long)(m0 + row) * DM + k0 + kc * 8;
      *(uint4*)(Ah + row * APAD + kc * 8) = *(const uint4*)(Ahi + off);
      *(uint4*)(Al + row * APAD + kc * 8) = *(const uint4*)(Alo + off);
    }
    stageB_tr(B, 1024, k0, n0, Bh, Bl, tid, 1);
    __syncthreads();
    bf16x8 ah[2], al[2], bh[4], bl[4];
#pragma unroll
    for (int i = 0; i < 2; i++) {
      ah[i] = *(const bf16x8*)(Ah + (wr * 32 + i * 16 + lrow) * APAD + lgrp * 8);
      al[i] = *(const bf16x8*)(Al + (wr * 32 + i * 16 + lrow) * APAD + lgrp * 8);
    }
#pragma unroll
    for (int j = 0; j < 4; j++) {
      bh[j] = *(const bf16x8*)(Bh + (wc * 64 + j * 16 + lrow) * APAD + lgrp * 8);
      bl[j] = *(const bf16x8*)(Bl + (wc * 64 + j * 16 + lrow) * APAD + lgrp * 8);
    }
#pragma unroll
    for (int i = 0; i < 2; i++)
#pragma unroll
      for (int j = 0; j < 4; j++) {
        acc[i][j] = __builtin_amdgcn_mfma_f32_16x16x32_bf16(ah[i], bh[j], acc[i][j], 0, 0, 0);
        acc[i][j] = __builtin_amdgcn_mfma_f32_16x16x32_bf16(ah[i], bl[j], acc[i][j], 0, 0, 0);
        acc[i][j] = __builtin_amdgcn_mfma_f32_16x16x32_bf16(al[i], bh[j], acc[i][j], 0, 0, 0);
      }
    __syncthreads();
  }
#pragma unroll
  for (int i = 0; i < 2; i++)
#pragma unroll
    for (int j = 0; j < 4; j++) {
      int col = n0 + wc * 64 + j * 16 + lrow;
#pragma unroll
      for (int jj = 0; jj < 4; jj++) {
        int r = m0 + wr * 32 + i * 16 + lgrp * 4 + jj;
        C[(long)r * DM + col] += acc[i][j][jj];
      }
    }
}

// ---------------- fused QKV + RoPE: 64x128 tile, grid 768 (3 blocks/CU)
__global__ __launch_bounds__(256) void k_gemm_qkv(
    const u16* __restrict__ Ahi, const u16* __restrict__ Alo,
    const float* __restrict__ Bq, const float* __restrict__ Bk,
    const float* __restrict__ Bv, u16* __restrict__ Chi, u16* __restrict__ Clo) {
  __shared__ u16 Ah[64 * APAD], Al[64 * APAD], Bh[128 * APAD], Bl[128 * APAD];
  int bid = blockIdx.x;
  int xcd = bid & 7, r = bid >> 3;
  int nb = xcd * 3 + r / 32;
  int m0 = (r & 31) * 64;
  const float* B = (nb < 8) ? Bq : (nb < 16) ? Bk : Bv;
  int bn0 = (nb & 7) * 128;
  int tid = threadIdx.x, lane = tid & 63, w = tid >> 6;
  int wr = w >> 1, wc = w & 1, lrow = lane & 15, lgrp = lane >> 4;
  f32x4 acc[2][4] = {};
  for (int k0 = 0; k0 < 1024; k0 += 32) {
    {
      int row = tid >> 2, kc = tid & 3;
      long off = (long)(m0 + row) * DM + k0 + kc * 8;
      *(uint4*)(Ah + row * APAD + kc * 8) = *(const uint4*)(Ahi + off);
      *(uint4*)(Al + row * APAD + kc * 8) = *(const uint4*)(Alo + off);
    }
    stageB_tr(B, 1024, k0, bn0, Bh, Bl, tid, 1);
    __syncthreads();
    bf16x8 ah[2], al[2], bh[4], bl[4];
#pragma unroll
    for (int i = 0; i < 2; i++) {
      ah[i] = *(const bf16x8*)(Ah + (wr * 32 + i * 16 + lrow) * APAD + lgrp * 8);
      al[i] = *(const bf16x8*)(Al + (wr * 32 + i * 16 + lrow) * APAD + lgrp * 8);
    }
#pragma unroll
    for (int j = 0; j < 4; j++) {
      bh[j] = *(const bf16x8*)(Bh + (wc * 64 + j * 16 + lrow) * APAD + lgrp * 8);
      bl[j] = *(const bf16x8*)(Bl + (wc * 64 + j * 16 + lrow) * APAD + lgrp * 8);
    }
#pragma unroll
    for (int i = 0; i < 2; i++)
#pragma unroll
      for (int j = 0; j < 4; j++) {
        acc[i][j] = __builtin_amdgcn_mfma_f32_16x16x32_bf16(ah[i], bh[j], acc[i][j], 0, 0, 0);
        acc[i][j] = __builtin_amdgcn_mfma_f32_16x16x32_bf16(ah[i], bl[j], acc[i][j], 0, 0, 0);
        acc[i][j] = __builtin_amdgcn_mfma_f32_16x16x32_bf16(al[i], bh[j], acc[i][j], 0, 0, 0);
      }
    __syncthreads();
  }
  if (nb < 16) {
    float inv1 = exp2f((float)lrow * (-13.287712379549449f / 32.0f));
    float inv2 = exp2f((float)(lrow + 16) * (-13.287712379549449f / 32.0f));
#pragma unroll
    for (int i = 0; i < 2; i++)
#pragma unroll
      for (int jj = 0; jj < 4; jj++) {
        int rr = m0 + wr * 32 + i * 16 + lgrp * 4 + jj;
        float s = (float)(rr & (SEQ - 1));
        float sn1, cs1, sn2, cs2;
        sincosf(s * inv1, &sn1, &cs1);
        sincosf(s * inv2, &sn2, &cs2);
        float q1 = acc[i][0][jj], q2 = acc[i][2][jj];
        acc[i][0][jj] = q1 * cs1 - q2 * sn1;
        acc[i][2][jj] = q1 * sn1 + q2 * cs1;
        float p1 = acc[i][1][jj], p2 = acc[i][3][jj];
        acc[i][1][jj] = p1 * cs2 - p2 * sn2;
        acc[i][3][jj] = p1 * sn2 + p2 * cs2;
      }
  }
#pragma unroll
  for (int i = 0; i < 2; i++)
#pragma unroll
    for (int j = 0; j < 4; j++) {
      int col = nb * 128 + wc * 64 + j * 16 + lrow;
#pragma unroll
      for (int jj = 0; jj < 4; jj++) {
        int rr = m0 + wr * 32 + i * 16 + lgrp * 4 + jj;
        float v = acc[i][j][jj];
        u16 hv = f2bf(v);
        Chi[(long)rr * 3072 + col] = hv;
        Clo[(long)rr * 3072 + col] = f2bf(v - bf2f(hv));
      }
    }
}

// ---------------- fused MoE up-projection + silu: gate AND up per block,
// 64x128 tile, grid 1280 (nb 0..15), writes hb hi/lo directly
template <int SPLIT>
__global__ __launch_bounds__(256) void k_w13(
    const u16* __restrict__ Ahi, const u16* __restrict__ Alo,
    const float* __restrict__ W1, const float* __restrict__ W3,
    const int* __restrict__ lists, const int* __restrict__ counts,
    const int* __restrict__ aoff,
    u16* __restrict__ hhi, u16* __restrict__ hlo) {
  int bid = blockIdx.x;
  int xcd = bid & 7, r = bid >> 3;      // r 0..159
  int nb = xcd * 2 + r / 80;            // 2 n-panels per XCD (0..15)
  int m0 = (r % 80) * 64;               // m fastest (80 panels of 64)
  int e = -1;
#pragma unroll
  for (int i = 0; i < NEXP; i++)
    if (m0 >= aoff[i] && m0 < aoff[i + 1]) e = i;
  if (e < 0) return;
  int lr0 = m0 - aoff[e];
  int Mc = counts[e];
  if (lr0 >= Mc) return;
  const float* B1 = W1 + (size_t)e * 1024 * 2048;
  const float* B3 = W3 + (size_t)e * 1024 * 2048;
  int bn0 = nb * 128;
  const int* lst = lists + e * TOK;
  __shared__ u16 Ah[64 * APAD], B1h[128 * APAD], B3h[128 * APAD];
  __shared__ u16 Al[SPLIT ? 64 * APAD : 1];
  __shared__ u16 B1l[SPLIT ? 128 * APAD : 1], B3l[SPLIT ? 128 * APAD : 1];
  int tid = threadIdx.x, lane = tid & 63, w = tid >> 6;
  int wr = w >> 1, wc = w & 1, lrow = lane & 15, lgrp = lane >> 4;
  f32x4 acc1[2][4] = {}, acc3[2][4] = {};
  for (int k0 = 0; k0 < 1024; k0 += 32) {
    {  // A: 64 gathered rows, single pass, shared by both GEMMs
      int row = tid >> 2, kc = tid & 3;
      uint4 vh = make_uint4(0, 0, 0, 0), vl = make_uint4(0, 0, 0, 0);
      if (lr0 + row < Mc) {
        long off = (long)lst[lr0 + row] * DM + k0 + kc * 8;
        vh = *(const uint4*)(Ahi + off);
        if (SPLIT) vl = *(const uint4*)(Alo + off);
      }
      *(uint4*)(Ah + row * APAD + kc * 8) = vh;
      if (SPLIT) *(uint4*)(Al + row * APAD + kc * 8) = vl;
    }
    stageB_tr(B1, 2048, k0, bn0, B1h, B1l, tid, SPLIT);
    stageB_tr(B3, 2048, k0, bn0, B3h, B3l, tid, SPLIT);
    __syncthreads();
    bf16x8 ah[2], al[2];
#pragma unroll
    for (int i = 0; i < 2; i++) {
      ah[i] = *(const bf16x8*)(Ah + (wr * 32 + i * 16 + lrow) * APAD + lgrp * 8);
      if (SPLIT) al[i] = *(const bf16x8*)(Al + (wr * 32 + i * 16 + lrow) * APAD + lgrp * 8);
    }
    {  // gate = A @ W1
      bf16x8 bh[4];
#pragma unroll
      for (int j = 0; j < 4; j++)
        bh[j] = *(const bf16x8*)(B1h + (wc * 64 + j * 16 + lrow) * APAD + lgrp * 8);
#pragma unroll
      for (int i = 0; i < 2; i++)
#pragma unroll
        for (int j = 0; j < 4; j++)
          acc1[i][j] = __builtin_amdgcn_mfma_f32_16x16x32_bf16(ah[i], bh[j], acc1[i][j], 0, 0, 0);
      if (SPLIT) {
        bf16x8 bl[4];
#pragma unroll
        for (int j = 0; j < 4; j++)
          bl[j] = *(const bf16x8*)(B1l + (wc * 64 + j * 16 + lrow) * APAD + lgrp * 8);
#pragma unroll
        for (int i = 0; i < 2; i++)
#pragma unroll
          for (int j = 0; j < 4; j++) {
            acc1[i][j] = __builtin_amdgcn_mfma_f32_16x16x32_bf16(ah[i], bl[j], acc1[i][j], 0, 0, 0);
            acc1[i][j] = __builtin_amdgcn_mfma_f32_16x16x32_bf16(al[i], bh[j], acc1[i][j], 0, 0, 0);
          }
      }
    }
    {  // up = A @ W3
      bf16x8 bh[4];
#pragma unroll
      for (int j = 0; j < 4; j++)
        bh[j] = *(const bf16x8*)(B3h + (wc * 64 + j * 16 + lrow) * APAD + lgrp * 8);
#pragma unroll
      for (int i = 0; i < 2; i++)
#pragma unroll
        for (int j = 0; j < 4; j++)
          acc3[i][j] = __builtin_amdgcn_mfma_f32_16x16x32_bf16(ah[i], bh[j], acc3[i][j], 0, 0, 0);
      if (SPLIT) {
        bf16x8 bl[4];
#pragma unroll
        for (int j = 0; j < 4; j++)
          bl[j] = *(const bf16x8*)(B3l + (wc * 64 + j * 16 + lrow) * APAD + lgrp * 8);
#pragma unroll
        for (int i = 0; i < 2; i++)
#pragma unroll
          for (int j = 0; j < 4; j++) {
            acc3[i][j] = __builtin_amdgcn_mfma_f32_16x16x32_bf16(ah[i], bl[j], acc3[i][j], 0, 0, 0);
            acc3[i][j] = __builtin_amdgcn_mfma_f32_16x16x32_bf16(al[i], bh[j], acc3[i][j], 0, 0, 0);
          }
      }
    }
    __syncthreads();
  }
#pragma unroll
  for (int i = 0; i < 2; i++)
#pragma unroll
    for (int j = 0; j < 4; j++) {
      int col = bn0 + wc * 64 + j * 16 + lrow;
#pragma unroll
      for (int jj = 0; jj < 4; jj++) {
        int rl = wr * 32 + i * 16 + lgrp * 4 + jj;
        if (lr0 + rl >= Mc) continue;
        float g = acc1[i][j][jj], u = acc3[i][j][jj];
        float o = g / (1.0f + __expf(-g)) * u;
        u16 hv = f2bf(o);
        hhi[(long)(m0 + rl) * 2048 + col] = hv;
        if (SPLIT) hlo[(long)(m0 + rl) * 2048 + col] = f2bf(o - bf2f(hv));
      }
    }
}

// ---------------- batched MoE down-projection: 64x128 tile, grid 640 (2.5/CU)
template <int SPLIT>
__global__ __launch_bounds__(256) void k_w2(
    const u16* __restrict__ Ahi, const u16* __restrict__ Alo,
    const float* __restrict__ W2,
    const int* __restrict__ counts, const int* __restrict__ aoff,
    float* __restrict__ y) {
  int bid = blockIdx.x;
  int n0 = (bid & 7) * 128;
  int m0 = (bid >> 3) * 64;
  int e = -1;
#pragma unroll
  for (int i = 0; i < NEXP; i++)
    if (m0 >= aoff[i] && m0 < aoff[i + 1]) e = i;
  if (e < 0) return;
  int lr0 = m0 - aoff[e];
  int Mc = counts[e];
  if (lr0 >= Mc) return;
  const float* B = W2 + (size_t)e * 2048 * 1024;
  __shared__ u16 Ah[64 * APAD], Bh[128 * APAD];
  __shared__ u16 Al[SPLIT ? 64 * APAD : 1], Bl[SPLIT ? 128 * APAD : 1];
  int tid = threadIdx.x, lane = tid & 63, w = tid >> 6;
  int wr = w >> 1, wc = w & 1, lrow = lane & 15, lgrp = lane >> 4;
  f32x4 acc[2][4] = {};
  for (int k0 = 0; k0 < 2048; k0 += 32) {
    {
      int row = tid >> 2, kc = tid & 3;
      long off = (long)(m0 + row) * 2048 + k0 + kc * 8;
      *(uint4*)(Ah + row * APAD + kc * 8) = *(const uint4*)(Ahi + off);
      if (SPLIT) *(uint4*)(Al + row * APAD + kc * 8) = *(const uint4*)(Alo + off);
    }
    stageB_tr(B, 1024, k0, n0, Bh, Bl, tid, SPLIT);
    __syncthreads();
    bf16x8 ah[2], bh[4];
#pragma unroll
    for (int i = 0; i < 2; i++)
      ah[i] = *(const bf16x8*)(Ah + (wr * 32 + i * 16 + lrow) * APAD + lgrp * 8);
#pragma unroll
    for (int j = 0; j < 4; j++)
      bh[j] = *(const bf16x8*)(Bh + (wc * 64 + j * 16 + lrow) * APAD + lgrp * 8);
#pragma unroll
    for (int i = 0; i < 2; i++)
#pragma unroll
      for (int j = 0; j < 4; j++)
        acc[i][j] = __builtin_amdgcn_mfma_f32_16x16x32_bf16(ah[i], bh[j], acc[i][j], 0, 0, 0);
    if (SPLIT) {
      bf16x8 al[2], bl[4];
#pragma unroll
      for (int i = 0; i < 2; i++)
        al[i] = *(const bf16x8*)(Al + (wr * 32 + i * 16 + lrow) * APAD + lgrp * 8);
#pragma unroll
      for (int j = 0; j < 4; j++)
        bl[j] = *(const bf16x8*)(Bl + (wc * 64 + j * 16 + lrow) * APAD + lgrp * 8);
#pragma unroll
      for (int i = 0; i < 2; i++)
#pragma unroll
        for (int j = 0; j < 4; j++) {
          acc[i][j] = __builtin_amdgcn_mfma_f32_16x16x32_bf16(ah[i], bl[j], acc[i][j], 0, 0, 0);
          acc[i][j] = __builtin_amdgcn_mfma_f32_16x16x32_bf16(al[i], bh[j], acc[i][j], 0, 0, 0);
        }
    }
    __syncthreads();
  }
#pragma unroll
  for (int i = 0; i < 2; i++)
#pragma unroll
    for (int j = 0; j < 4; j++) {
      int col = n0 + wc * 64 + j * 16 + lrow;
#pragma unroll
      for (int jj = 0; jj < 4; jj++) {
        int rl = wr * 32 + i * 16 + lgrp * 4 + jj;
        if (lr0 + rl >= Mc) continue;
        y[(long)(m0 + rl) * DM + col] = acc[i][j][jj];
      }
    }
}

// ---------------- combine + next-layer norm fused (+zero counts when !FINAL)
template <int FINAL>
__global__ __launch_bounds__(256) void k_combine_norm(const float* __restrict__ y,
    const int* __restrict__ aoff, const int* __restrict__ tok_e,
    const int* __restrict__ tok_pos, const float* __restrict__ tok_gate,
    float* __restrict__ x, const float* __restrict__ wnext,
    u16* __restrict__ ohi, u16* __restrict__ olo, int* __restrict__ counts) {
  int t = blockIdx.x;
  if (!FINAL && t == 0 && threadIdx.x < NEXP) counts[threadIdx.x] = 0;
  float4 acc = ((float4*)(x + (long)t * DM))[threadIdx.x];
#pragma unroll
  for (int j = 0; j < 2; j++) {
    int e = tok_e[t * 2 + j];
    long g = aoff[e] + tok_pos[t * 2 + j];
    float gt = tok_gate[t * 2 + j];
    float4 yv = ((const float4*)(y + g * DM))[threadIdx.x];
    acc.x += gt * yv.x; acc.y += gt * yv.y;
    acc.z += gt * yv.z; acc.w += gt * yv.w;
  }
  ((float4*)(x + (long)t * DM))[threadIdx.x] = acc;
  if (FINAL) norm_emit_b(acc, wnext, ohi, t);
  else norm_emit_hl(acc, wnext, ohi, olo, t);
}

// ---------------- logits fragment compute
__device__ __forceinline__ void logits_mma(const u16* As, const u16* Bs,
    f32x4 (&acc)[4][4], int wr, int wc, int lrow, int lgrp) {
  bf16x8 af[4], bfr[4];
#pragma unroll
  for (int i = 0; i < 4; i++) {
    af[i] = *(const bf16x8*)(As + (wr * 64 + i * 16 + lrow) * APAD + lgrp * 8);
    bfr[i] = *(const bf16x8*)(Bs + (wc * 64 + i * 16 + lrow) * APAD + lgrp * 8);
  }
#pragma unroll
  for (int i = 0; i < 4; i++)
#pragma unroll
    for (int j = 0; j < 4; j++)
      acc[i][j] = __builtin_amdgcn_mfma_f32_16x16x32_bf16(af[i], bfr[j], acc[i][j], 0, 0, 0);
}

// ---------------- logits GEMM (r14 structure, measured 188-194 us)
__global__ __launch_bounds__(512) void k_logits(
    const u16* __restrict__ A, const u16* __restrict__ Bt,
    float* __restrict__ C) {
  __shared__ u16 AsA[256 * APAD], BsA[128 * APAD];
  __shared__ u16 AsB[256 * APAD], BsB[128 * APAD];
  int bid = blockIdx.x;
  int xcd = bid & 7, rank = bid >> 3;
  int bx = xcd * 32 + (rank >> 3);
  int by = rank & 7;
  if (bx >= VOCAB / 128) return;
  int m0 = by * 256, n0 = bx * 128;
  int tid = threadIdx.x, lane = tid & 63, w = tid >> 6;
  int wr = w >> 1, wc = w & 1;
  int lrow = lane & 15, lgrp = lane >> 4;
  int arow = tid >> 2, akc = tid & 3;
  f32x4 acc[4][4] = {};
  const u16* Ap = A + (long)(m0 + arow) * 1024 + akc * 8;
  const u16* Ap2 = A + (long)(m0 + arow + 128) * 1024 + akc * 8;
  const u16* Bp = Bt + (long)(n0 + arow) * 1024 + akc * 8;
  uint4 a0 = *(const uint4*)(Ap);
  uint4 a1 = *(const uint4*)(Ap2);
  uint4 b0 = *(const uint4*)(Bp);
  *(uint4*)(AsA + arow * APAD + akc * 8) = a0;
  *(uint4*)(AsA + (arow + 128) * APAD + akc * 8) = a1;
  *(uint4*)(BsA + arow * APAD + akc * 8) = b0;
  __syncthreads();
  for (int kt = 0; kt < 32; kt += 2) {
    {
      int k0 = (kt + 1) * 32;
      a0 = *(const uint4*)(Ap + k0);
      a1 = *(const uint4*)(Ap2 + k0);
      b0 = *(const uint4*)(Bp + k0);
    }
    logits_mma(AsA, BsA, acc, wr, wc, lrow, lgrp);
    *(uint4*)(AsB + arow * APAD + akc * 8) = a0;
    *(uint4*)(AsB + (arow + 128) * APAD + akc * 8) = a1;
    *(uint4*)(BsB + arow * APAD + akc * 8) = b0;
    __syncthreads();
    if (kt + 2 < 32) {
      int k0 = (kt + 2) * 32;
      a0 = *(const uint4*)(Ap + k0);
      a1 = *(const uint4*)(Ap2 + k0);
      b0 = *(const uint4*)(Bp + k0);
    }
    logits_mma(AsB, BsB, acc, wr, wc, lrow, lgrp);
    if (kt + 2 < 32) {
      *(uint4*)(AsA + arow * APAD + akc * 8) = a0;
      *(uint4*)(AsA + (arow + 128) * APAD + akc * 8) = a1;
      *(uint4*)(BsA + arow * APAD + akc * 8) = b0;
    }
    __syncthreads();
  }
#pragma unroll
  for (int i = 0; i < 4; i++)
#pragma unroll
    for (int j = 0; j < 4; j++) {
      int col = n0 + wc * 64 + j * 16 + lrow;
#pragma unroll
      for (int jj = 0; jj < 4; jj++) {
        int r = m0 + wr * 64 + i * 16 + lgrp * 4 + jj;
        C[(long)r * VOCAB + col] = acc[i][j][jj];
      }
    }
}

// ---------------- router fused with moe rmsnorm: top-2 + emit xn hi/lo
__global__ __launch_bounds__(256) void k_router_norm(const float* __restrict__ x,
    const float* __restrict__ nw, const float* __restrict__ rw,
    int* __restrict__ counts, int* __restrict__ lists,
    int* __restrict__ tok_e, int* __restrict__ tok_pos,
    float* __restrict__ tok_gate,
    u16* __restrict__ ohi, u16* __restrict__ olo) {
  int t = blockIdx.x * 4 + (threadIdx.x >> 6);
  int lane = threadIdx.x & 63;
  const float* xr = x + (long)t * DM;
  float xv[16], wv[16];
  float ss = 0.0f;
  float p[8] = {0, 0, 0, 0, 0, 0, 0, 0};
#pragma unroll
  for (int i = 0; i < 16; i++) {
    int d = lane + 64 * i;
    xv[i] = xr[d];
    wv[i] = nw[d];
    ss += xv[i] * xv[i];
    float xw = xv[i] * wv[i];
#pragma unroll
    for (int e = 0; e < 8; e++) p[e] += xw * rw[e * DM + d];
  }
  for (int off = 32; off; off >>= 1) ss += __shfl_xor(ss, off);
#pragma unroll
  for (int e = 0; e < 8; e++)
    for (int off = 32; off; off >>= 1) p[e] += __shfl_xor(p[e], off);
  float sc = rsqrtf(ss * (1.0f / 1024.0f) + 1e-6f);
#pragma unroll
  for (int i = 0; i < 16; i++) {
    int d = lane + 64 * i;
    float o = xv[i] * sc * wv[i];
    u16 h = f2bf(o);
    ohi[(long)t * DM + d] = h;
    olo[(long)t * DM + d] = f2bf(o - bf2f(h));
  }
  if (lane == 0) {
    int e0 = 0, e1 = -1;
    float v0 = -__builtin_inff(), v1 = -__builtin_inff();
    for (int e = 0; e < 8; e++) {
      float pe = p[e] * sc;
      if (pe > v0) { v1 = v0; e1 = e0; v0 = pe; e0 = e; }
      else if (pe > v1) { v1 = pe; e1 = e; }
    }
    float w0 = 1.0f / (1.0f + expf(v1 - v0));
    int pos0 = atomicAdd(&counts[e0], 1);
    lists[e0 * TOK + pos0] = t;
    tok_e[t * 2] = e0; tok_pos[t * 2] = pos0; tok_gate[t * 2] = w0;
    int pos1 = atomicAdd(&counts[e1], 1);
    lists[e1 * TOK + pos1] = t;
    tok_e[t * 2 + 1] = e1; tok_pos[t * 2 + 1] = pos1; tok_gate[t * 2 + 1] = 1.0f - w0;
  }
}

// ---------------- 64-aligned exclusive prefix of counts
__global__ void k_offsets(const int* __restrict__ counts, int* __restrict__ aoff) {
  if (threadIdx.x == 0 && blockIdx.x == 0) {
    int a = 0;
    for (int e = 0; e < NEXP; e++) {
      aoff[e] = a;
      a += (counts[e] + 63) & ~63;
    }
    aoff[NEXP] = a;
  }
}

extern "C" void kernel_launch(void* const* d_in, const int* in_sizes, int n_in,
                              void* d_out, int out_size, void* d_ws, size_t ws_size,
                              hipStream_t stream) {
  (void)in_sizes; (void)n_in; (void)out_size; (void)ws_size;
  const int* tokens = (const int*)d_in[0];
  const float* embed = (const float*)d_in[1];
  const float* attn_nw = (const float*)d_in[2];
  const float* wq = (const float*)d_in[3];
  const float* wk = (const float*)d_in[4];
  const float* wv = (const float*)d_in[5];
  const float* wo = (const float*)d_in[6];
  const float* moe_nw = (const float*)d_in[7];
  const float* rw = (const float*)d_in[8];
  const float* w1 = (const float*)d_in[9];
  const float* w2 = (const float*)d_in[10];
  const float* w3 = (const float*)d_in[11];
  const float* fin_nw = (const float*)d_in[12];
  float* out = (float*)d_out;

  // ---- scratch carved from d_out (262 MB; all dead before final logits GEMM)
  char* ob = (char*)d_out;
  auto carve = [&](size_t bytes) { char* r = ob; ob += (bytes + 255) & ~(size_t)255; return r; };
  u16*   qkv_hi = (u16*)carve((size_t)TOK * 3072 * 2);
  u16*   qkv_lo = (u16*)carve((size_t)TOK * 3072 * 2);
  u16*   ctx_hi = (u16*)carve((size_t)TOK * DM * 2);
  u16*   ctx_lo = (u16*)carve((size_t)TOK * DM * 2);
  float* x      = (float*)carve((size_t)TOK * DM * 4);
  u16*   hb_hi  = (u16*)carve((size_t)SLOTS * 2048 * 2);
  u16*   hb_lo  = (u16*)carve((size_t)SLOTS * 2048 * 2);
  float* y      = (float*)carve((size_t)SLOTS * 1024 * 4);
  int*   counts  = (int*)carve(NEXP * 4);
  int*   aoff    = (int*)carve((NEXP + 1) * 4);
  int*   lists   = (int*)carve((size_t)NEXP * TOK * 4);
  int*   tok_e   = (int*)carve((size_t)TOK * 2 * 4);
  int*   tok_pos = (int*)carve((size_t)TOK * 2 * 4);
  float* tok_gate= (float*)carve((size_t)TOK * 2 * 4);
  // ---- d_ws: buffers the final GEMM reads while d_out is being written
  char* wp = (char*)d_ws;
  auto wcarve = [&](size_t bytes) { char* r = wp; wp += (bytes + 255) & ~(size_t)255; return r; };
  u16* xn_hi = (u16*)wcarve((size_t)TOK * DM * 2);
  u16* xn_lo = (u16*)wcarve((size_t)TOK * DM * 2);
  u16* xnb   = (u16*)wcarve((size_t)TOK * DM * 2);
  u16* embB  = (u16*)wcarve((size_t)VOCAB * DM * 2);

  k_f2bf<<<4096, 256, 0, stream>>>(embed, embB, (long)VOCAB * DM / 4);
  k_gather_norm<<<TOK, 256, 0, stream>>>(tokens, embed, attn_nw, x, xn_hi, xn_lo, counts);

  for (int l = 0; l < NL; l++) {
    k_gemm_qkv<<<768, 256, 0, stream>>>(xn_hi, xn_lo,
        wq + (size_t)l * DM * DM, wk + (size_t)l * DM * DM, wv + (size_t)l * DM * DM,
        qkv_hi, qkv_lo);
    k_attn<<<512, 256, 0, stream>>>(qkv_hi, qkv_lo, ctx_hi, ctx_lo);
    k_wo<<<256, 256, 0, stream>>>(ctx_hi, ctx_lo, wo + (size_t)l * DM * DM, x);

    k_router_norm<<<TOK / 4, 256, 0, stream>>>(x, moe_nw + (size_t)l * DM,
        rw + (size_t)l * NEXP * DM, counts, lists, tok_e, tok_pos, tok_gate,
        xn_hi, xn_lo);
    k_offsets<<<1, 64, 0, stream>>>(counts, aoff);
    if (l < NL - 1) {
      k_w13<1><<<1280, 256, 0, stream>>>(xn_hi, xn_lo,
          w1 + (size_t)l * NEXP * DM * 2048, w3 + (size_t)l * NEXP * DM * 2048,
          lists, counts, aoff, hb_hi, hb_lo);
      k_w2<1><<<640, 256, 0, stream>>>(hb_hi, hb_lo,
          w2 + (size_t)l * NEXP * 2048 * DM, counts, aoff, y);
      k_combine_norm<0><<<TOK, 256, 0, stream>>>(y, aoff, tok_e, tok_pos, tok_gate,
          x, attn_nw + (size_t)(l + 1) * DM, xn_hi, xn_lo, counts);
    } else {
      k_w13<0><<<1280, 256, 0, stream>>>(xn_hi, xn_lo,
          w1 + (size_t)l * NEXP * DM * 2048, w3 + (size_t)l * NEXP * DM * 2048,
          lists, counts, aoff, hb_hi, nullptr);
      k_w2<0><<<640, 256, 0, stream>>>(hb_hi, hb_lo,
          w2 + (size_t)l * NEXP * 2048 * DM, counts, aoff, y);
      k_combine_norm<1><<<TOK, 256, 0, stream>>>(y, aoff, tok_e, tok_pos, tok_gate,
          x, fin_nw, xnb, nullptr, nullptr);
    }
  }
  k_logits<<<2048, 512, 0, stream>>>(xnb, embB, out);
}